// Round 3
// baseline (392.571 us; speedup 1.0000x reference)
//
#include <hip/hip_runtime.h>
#include <math.h>

// Problem constants
#define NXg 48
#define NYg 48
#define Tg 512
#define NG 20000              // B*NE, batch folded
#define H1g 64
#define H2g 128

// Tiling
#define TT 32                 // ticks per bin
#define NBINS 16
#define RCAP 3072             // per-bin record capacity (max count ~2650)
#define TCAP 3072             // per-(bin,tile) list capacity (max ~2300)
#define SPLIT 6               // split-K over tile lists
#define KSPLIT 8              // k_electron H2 split
#define RSTRIDE 48            // floats per record: 32 prof + x + y + pad (192B, 64B-aligned)

typedef float vf16 __attribute__((ext_vector_type(16)));

// ws layout
#define OFF_REC   0                                              //  9,437,184
#define OFF_PART  (OFF_REC   + (size_t)NBINS*RCAP*RSTRIDE*4)     // 28,311,552
#define OFF_RESP8 (OFF_PART  + (size_t)SPLIT*9*NBINS*2048*16)    //    640,000
#define OFF_EDATA (OFF_RESP8 + (size_t)NG*8*4)                   //    320,000
#define OFF_LIST  (OFF_EDATA + (size_t)NG*16)                    //    196,608
#define OFF_TLIST (OFF_LIST  + (size_t)NBINS*RCAP*4)             //  1,769,472
#define OFF_CNT   (OFF_TLIST + (size_t)NBINS*9*TCAP*4)           //        640
// total ~40.7 MB

// ---------------------------------------------------------------------------
// Kernel 1: per-electron MLP partials (H2 split 8-way) + per-bin lists.
// W2 accessed k-inner -> one s_load_dwordx16 per row (64 wide scalar loads).
// ---------------------------------------------------------------------------
__global__ __launch_bounds__(256) void k_electron(
    const float* __restrict__ sim, const float* __restrict__ zpos,
    const float* __restrict__ mask,
    const float* __restrict__ W1, const float* __restrict__ b1,
    const float* __restrict__ W2, const float* __restrict__ b2,
    const float* __restrict__ W3, const float* __restrict__ b3,
    float4* __restrict__ edata, float* __restrict__ resp8,
    int* __restrict__ cnt, int* __restrict__ list)
{
    int g = blockIdx.x * 256 + threadIdx.x;
    int q = blockIdx.y;               // H2 chunk 0..7
    if (g >= NG) return;

    float x0 = sim[2 * g], x1 = sim[2 * g + 1];

    float h1[H1g];
#pragma unroll
    for (int j = 0; j < H1g; ++j)
        h1[j] = fmaxf(fmaf(x0, W1[j], fmaf(x1, W1[H1g + j], b1[j])), 0.0f);

    int k0 = q * 16;
    float a[16];
    const vf16 bb = *(const vf16*)&b2[k0];
#pragma unroll
    for (int u = 0; u < 16; ++u) a[u] = bb[u];
    for (int j = 0; j < H1g; ++j) {
        float h = h1[j];
        vf16 w = *(const vf16*)&W2[j * H2g + k0];    // 64B-aligned wide scalar load
#pragma unroll
        for (int u = 0; u < 16; ++u) a[u] = fmaf(h, w[u], a[u]);
    }
    float r = (q == 0) ? b3[0] : 0.0f;
#pragma unroll
    for (int u = 0; u < 16; ++u) r = fmaf(fmaxf(a[u], 0.0f), W3[k0 + u], r);
    resp8[g * 8 + q] = r;

    if (q == 0) {
        float z = zpos[g];
        edata[g] = make_float4(x0, x1, z, mask[g]);
        // bins with min |t-z| <= sqrt(180) (dropped time terms < e^-18)
        int jlo = (int)ceilf((z - 44.5f) * (1.0f / 32.0f));
        int jhi = (int)floorf((z + 13.5f) * (1.0f / 32.0f));
        jlo = max(jlo, 0);
        jhi = min(jhi, NBINS - 1);
        for (int j = jlo; j <= jhi; ++j) {
            int p = atomicAdd(&cnt[j], 1);
            if (p < RCAP) list[j * RCAP + p] = g;
        }
    }
}

// ---------------------------------------------------------------------------
// Kernel 2: build 192B electron records (amp-folded 32-tick profile + pos)
// and per-(bin,tile) prefiltered lists (rect distance <= 36*es^2).
// 4 threads per entry, 8 ticks each.
// ---------------------------------------------------------------------------
__global__ __launch_bounds__(256) void k_prof(
    const float4* __restrict__ edata, const float* __restrict__ resp8,
    const int* __restrict__ cnt, const int* __restrict__ list,
    const float* __restrict__ el_spread,
    float* __restrict__ rec, int* __restrict__ tcnt, int* __restrict__ tlist)
{
    int bin = blockIdx.y;
    int i = blockIdx.x * 64 + (threadIdx.x >> 2);
    int sub = threadIdx.x & 3;
    int count = min(cnt[bin], RCAP);
    if (i >= count) return;

    int g = list[bin * RCAP + i];
    float4 E = edata[g];
    const float4* rp = (const float4*)&resp8[g * 8];
    float4 r0 = rp[0], r1 = rp[1];
    float resp = ((r0.x + r0.y) + (r0.z + r0.w)) + ((r1.x + r1.y) + (r1.z + r1.w));
    float es = el_spread[0];
    float amp = resp * E.w * (100.0f / (es * 2.5066f)) *
                (0.3989422804f / 2.23606797749979f);
    int tl = sub * 8;
    float tb = (float)(bin * TT + tl) - E.z;
    float v[8];
#pragma unroll
    for (int u = 0; u < 8; ++u) {
        float d = tb + (float)u;
        v[u] = amp * __expf(-0.1f * d * d);
    }
    float* R = rec + ((size_t)bin * RCAP + i) * RSTRIDE;
    float4* R4 = (float4*)(R + tl);
    R4[0] = make_float4(v[0], v[1], v[2], v[3]);
    R4[1] = make_float4(v[4], v[5], v[6], v[7]);
    if (sub == 0) {
        R[32] = E.x;
        R[33] = E.y;
        float rcut2 = 36.0f * es * es;     // matches e^-18 in-loop cutoff
        for (int ty = 0; ty < 3; ++ty) {
            float ylo = -1.0f + (2.0f / 47.0f) * (ty * 16);
            float yhi = -1.0f + (2.0f / 47.0f) * (ty * 16 + 15);
            float dy = E.y - fminf(fmaxf(E.y, ylo), yhi);
            for (int tx = 0; tx < 3; ++tx) {
                float xlo = -1.0f + (2.0f / 47.0f) * (tx * 16);
                float xhi = -1.0f + (2.0f / 47.0f) * (tx * 16 + 15);
                float dx = E.x - fminf(fmaxf(E.x, xlo), xhi);
                if (fmaf(dx, dx, dy * dy) <= rcut2) {
                    int t = ty * 3 + tx;
                    int p = atomicAdd(&tcnt[bin * 9 + t], 1);
                    if (p < TCAP) tlist[(bin * 9 + t) * TCAP + p] = i;
                }
            }
        }
    }
}

// ---------------------------------------------------------------------------
// Kernel 3: main rank-1 accumulation. Wave-uniform record loads -> 3 wide
// s_loads per electron; unroll-2 double buffer (no copy movs); idx prefetch
// 2 pairs ahead. Thread = 1 sensor, 32-tick register accumulator.
// ---------------------------------------------------------------------------
struct RecR { vf16 a, b; float px, py; };

__device__ __forceinline__ void loadRec(RecR& R, const float* __restrict__ rb, int idx) {
    const float* p = rb + (size_t)idx * RSTRIDE;
    R.a = *(const vf16*)p;
    R.b = *(const vf16*)(p + 16);
    R.px = p[32];
    R.py = p[33];
}

__global__ __launch_bounds__(256) void k_main(
    const float* __restrict__ rec, const int* __restrict__ tcnt,
    const int* __restrict__ tlist,
    const float* __restrict__ el_spread, const float* __restrict__ sensors,
    float4* __restrict__ part)
{
    int tid = threadIdx.x;
    int tile = blockIdx.x;        // 0..8
    int bin = blockIdx.y;         // 0..15
    int split = blockIdx.z;       // 0..SPLIT-1

    int lx = tid & 15, ly = tid >> 4;
    int x = (tile % 3) * 16 + lx;
    int y = (tile / 3) * 16 + ly;
    float sx = sensors[(x * NYg + y) * 2 + 0];
    float sy = sensors[(x * NYg + y) * 2 + 1];
    float es = el_spread[0];
    float inv2 = -0.5f / (es * es);

    int count = min(tcnt[bin * 9 + tile], TCAP);
    int start = count * split / SPLIT;
    int end = count * (split + 1) / SPLIT;
    const int* tl = &tlist[(bin * 9 + tile) * TCAP];
    const float* rb = rec + (size_t)bin * RCAP * RSTRIDE;

    float acc[TT];
#pragma unroll
    for (int t = 0; t < TT; ++t) acc[t] = 0.0f;

#define COMPUTE(R)                                                        \
    {                                                                     \
        float dx = sx - R.px, dy = sy - R.py;                             \
        float expo = inv2 * fmaf(dx, dx, dy * dy);                        \
        if (__any(expo > -18.0f)) {                                       \
            float c = expo > -18.0f ? __expf(expo) : 0.0f;                \
            _Pragma("unroll")                                             \
            for (int u = 0; u < 16; ++u) acc[u] = fmaf(c, R.a[u], acc[u]);\
            _Pragma("unroll")                                             \
            for (int u = 0; u < 16; ++u)                                  \
                acc[16 + u] = fmaf(c, R.b[u], acc[16 + u]);               \
        }                                                                 \
    }

    if (start < end) {
        int e1 = end - 1;
        int iB = tl[min(start + 1, e1)];
        int jA = tl[min(start + 2, e1)];
        int jB = tl[min(start + 3, e1)];
        RecR A, B;
        loadRec(A, rb, tl[start]);
        int i = start;
        for (; i + 1 < end; i += 2) {
            loadRec(B, rb, iB);
            int kA = tl[min(i + 4, e1)];
            int kB = tl[min(i + 5, e1)];
            COMPUTE(A);
            loadRec(A, rb, jA);
            COMPUTE(B);
            iB = jB; jA = kA; jB = kB;
        }
        if (i < end) COMPUTE(A);     // odd tail (A holds rec[i])
    }
#undef COMPUTE

    float4* pp = part + ((((size_t)split * 9 + tile) * NBINS + bin) * 2048);
#pragma unroll
    for (int u = 0; u < 8; ++u)
        pp[u * 256 + tid] =
            make_float4(acc[4 * u], acc[4 * u + 1], acc[4 * u + 2], acc[4 * u + 3]);
}

// ---------------------------------------------------------------------------
// Kernel 4: reduce split-K partials into output.
// ---------------------------------------------------------------------------
__global__ __launch_bounds__(256) void k_reduce(
    const float4* __restrict__ part, float* __restrict__ out)
{
    int tile = blockIdx.x, bin = blockIdx.y, tid = threadIdx.x;
    int lx = tid & 15, ly = tid >> 4;
    int x = (tile % 3) * 16 + lx;
    int y = (tile / 3) * 16 + ly;
    float* op = out + ((size_t)(x * NYg + y)) * Tg + bin * TT;

#pragma unroll
    for (int u = 0; u < 8; ++u) {
        float4 s = make_float4(0.f, 0.f, 0.f, 0.f);
        for (int sp = 0; sp < SPLIT; ++sp) {
            float4 v = part[(((size_t)sp * 9 + tile) * NBINS + bin) * 2048 +
                            u * 256 + tid];
            s.x += v.x; s.y += v.y; s.z += v.z; s.w += v.w;
        }
        *(float4*)(op + u * 4) = s;
    }
}

// ---------------------------------------------------------------------------
extern "C" void kernel_launch(void* const* d_in, const int* in_sizes, int n_in,
                              void* d_out, int out_size, void* d_ws, size_t ws_size,
                              hipStream_t stream)
{
    const float* sim       = (const float*)d_in[0];
    const float* zpos      = (const float*)d_in[1];
    const float* mask      = (const float*)d_in[2];
    const float* W1        = (const float*)d_in[3];
    const float* b1        = (const float*)d_in[4];
    const float* W2        = (const float*)d_in[5];
    const float* b2        = (const float*)d_in[6];
    const float* W3        = (const float*)d_in[7];
    const float* b3        = (const float*)d_in[8];
    const float* el_spread = (const float*)d_in[9];
    const float* sensors   = (const float*)d_in[10];
    float* out = (float*)d_out;

    char* ws = (char*)d_ws;
    float*  rec   = (float*)(ws + OFF_REC);
    float4* part  = (float4*)(ws + OFF_PART);
    float*  resp8 = (float*)(ws + OFF_RESP8);
    float4* edata = (float4*)(ws + OFF_EDATA);
    int*    list  = (int*)(ws + OFF_LIST);
    int*    tlist = (int*)(ws + OFF_TLIST);
    int*    cnt   = (int*)(ws + OFF_CNT);
    int*    tcnt  = cnt + NBINS;

    hipMemsetAsync(cnt, 0, (NBINS + NBINS * 9) * sizeof(int), stream);

    k_electron<<<dim3((NG + 255) / 256, KSPLIT), 256, 0, stream>>>(
        sim, zpos, mask, W1, b1, W2, b2, W3, b3, edata, resp8, cnt, list);

    k_prof<<<dim3(RCAP / 64, NBINS), 256, 0, stream>>>(
        edata, resp8, cnt, list, el_spread, rec, tcnt, tlist);

    k_main<<<dim3(9, NBINS, SPLIT), 256, 0, stream>>>(
        rec, tcnt, tlist, el_spread, sensors, part);

    k_reduce<<<dim3(9, NBINS), 256, 0, stream>>>(part, out);
}

// Round 4
// 254.684 us; speedup vs baseline: 1.5414x; 1.5414x over previous
//
#include <hip/hip_runtime.h>
#include <math.h>

// Problem constants
#define NXg 48
#define NYg 48
#define Tg 512
#define NG 20000              // B*NE, batch folded
#define H1g 64
#define H2g 128

// Tiling
#define TT 32                 // ticks per bin
#define NBINS 16
#define RCAP 3072             // per-bin list capacity (max count ~2650)
#define CCAP (RCAP / 32)      // 96 K-chunks max per bin
#define SPLIT 3               // split-K over chunks
#define KSPLIT 8              // k_electron H2 split
#define NSB 36                // sensor blocks of 64 (36*64 = 2304)

typedef float vf16 __attribute__((ext_vector_type(16)));
typedef _Float16 half8 __attribute__((ext_vector_type(8)));
typedef float floatx4 __attribute__((ext_vector_type(4)));

// ws layout (bytes)
#define OFF_BFRAG 0                                   //  6,291,456 (16*96*4*512 f16)
#define OFF_POSC  (OFF_BFRAG + (size_t)NBINS*CCAP*4*512*2)
#define OFF_PART  (OFF_POSC  + (size_t)NBINS*RCAP*8)  // 14,155,776
#define OFF_RESP8 (OFF_PART  + (size_t)SPLIT*NSB*NBINS*2048*4)
#define OFF_EDATA (OFF_RESP8 + (size_t)NG*8*4)
#define OFF_LIST  (OFF_EDATA + (size_t)NG*16)
#define OFF_CNT   (OFF_LIST  + (size_t)NBINS*RCAP*4)
// total ~22 MB

// ---------------------------------------------------------------------------
// Kernel 1: per-electron MLP partials (H2 split 8-way) + per-bin lists.
// (unchanged from R3 — verified correct)
// ---------------------------------------------------------------------------
__global__ __launch_bounds__(256) void k_electron(
    const float* __restrict__ sim, const float* __restrict__ zpos,
    const float* __restrict__ mask,
    const float* __restrict__ W1, const float* __restrict__ b1,
    const float* __restrict__ W2, const float* __restrict__ b2,
    const float* __restrict__ W3, const float* __restrict__ b3,
    float4* __restrict__ edata, float* __restrict__ resp8,
    int* __restrict__ cnt, int* __restrict__ list)
{
    int g = blockIdx.x * 256 + threadIdx.x;
    int q = blockIdx.y;
    if (g >= NG) return;

    float x0 = sim[2 * g], x1 = sim[2 * g + 1];

    float h1[H1g];
#pragma unroll
    for (int j = 0; j < H1g; ++j)
        h1[j] = fmaxf(fmaf(x0, W1[j], fmaf(x1, W1[H1g + j], b1[j])), 0.0f);

    int k0 = q * 16;
    float a[16];
    const vf16 bb = *(const vf16*)&b2[k0];
#pragma unroll
    for (int u = 0; u < 16; ++u) a[u] = bb[u];
    for (int j = 0; j < H1g; ++j) {
        float h = h1[j];
        vf16 w = *(const vf16*)&W2[j * H2g + k0];
#pragma unroll
        for (int u = 0; u < 16; ++u) a[u] = fmaf(h, w[u], a[u]);
    }
    float r = (q == 0) ? b3[0] : 0.0f;
#pragma unroll
    for (int u = 0; u < 16; ++u) r = fmaf(fmaxf(a[u], 0.0f), W3[k0 + u], r);
    resp8[g * 8 + q] = r;

    if (q == 0) {
        float z = zpos[g];
        edata[g] = make_float4(x0, x1, z, mask[g]);
        // bins with min |t-z| <= sqrt(180): dropped time terms < e^-18
        int jlo = (int)ceilf((z - 44.5f) * (1.0f / 32.0f));
        int jhi = (int)floorf((z + 13.5f) * (1.0f / 32.0f));
        jlo = max(jlo, 0);
        jhi = min(jhi, NBINS - 1);
        for (int j = jlo; j <= jhi; ++j) {
            int p = atomicAdd(&cnt[j], 1);
            if (p < RCAP) list[j * RCAP + p] = g;
        }
    }
}

// ---------------------------------------------------------------------------
// Kernel 2: build MFMA B-fragments (split-2 f16 hi/lo, amp-folded time
// profiles) pre-packed in exact per-lane fragment order, + chunk-padded
// electron positions. 32 threads per list entry (one per tick).
// B layout for 16x16x32_f16: lane = quad*16 + n (n = tick&15), element
// j = klocal&7, k = quad*8 + j. Sections: [h nt0][h nt1][l nt0][l nt1].
// ---------------------------------------------------------------------------
__global__ __launch_bounds__(256) void k_prof(
    const float4* __restrict__ edata, const float* __restrict__ resp8,
    const int* __restrict__ cnt, const int* __restrict__ list,
    const float* __restrict__ el_spread,
    _Float16* __restrict__ bfrag, float2* __restrict__ posc)
{
    int bin = blockIdx.y;
    int tid = threadIdx.x;
    int i = blockIdx.x * 8 + (tid >> 5);      // list position
    int t = tid & 31;                          // tick within bin
    int count = min(cnt[bin], RCAP);
    int npad = (count + 31) & ~31;
    if (i >= npad) return;

    int ch = i >> 5, kl = i & 31;
    int quad = kl >> 3, jj = kl & 7;
    int lane = quad * 16 + (t & 15), nt = t >> 4;
    size_t base = ((size_t)(bin * CCAP + ch)) * 4 * 512;   // f16 units
    size_t hidx = base + (size_t)nt * 512 + lane * 8 + jj;
    size_t lidx = base + (size_t)(2 + nt) * 512 + lane * 8 + jj;

    if (i < count) {
        int g = list[bin * RCAP + i];
        float4 E = edata[g];
        const float4* rp = (const float4*)&resp8[g * 8];
        float4 r0 = rp[0], r1 = rp[1];
        float resp = ((r0.x + r0.y) + (r0.z + r0.w)) +
                     ((r1.x + r1.y) + (r1.z + r1.w));
        float es = el_spread[0];
        float amp = resp * E.w * (100.0f / (es * 2.5066f)) *
                    (0.3989422804f / 2.23606797749979f);
        float d = (float)(bin * TT + t) - E.z;
        float v = amp * __expf(-0.1f * d * d);
        _Float16 h = (_Float16)v;
        bfrag[hidx] = h;
        bfrag[lidx] = (_Float16)(v - (float)h);
        if (t == 0) posc[(size_t)bin * RCAP + i] = make_float2(E.x, E.y);
    } else {
        bfrag[hidx] = (_Float16)0.0f;
        bfrag[lidx] = (_Float16)0.0f;
        if (t == 0) posc[(size_t)bin * RCAP + i] = make_float2(1.0e3f, 1.0e3f);
        // far pos -> exp underflows to 0, no NaN; B already zero
    }
}

// ---------------------------------------------------------------------------
// Kernel 3: MFMA main loop. Per bin: C[2304 x 32] += A[2304 x K] * B[K x 32].
// A (spatial gaussian) computed in-register (8 exps/lane/chunk), split into
// f16 hi+lo; B loaded as pre-packed fragments (coalesced b128, vmcnt
// pipelined by compiler). D += Ah*Bh + Al*Bh + Ah*Bl (~fp32 accuracy).
// Block = 4 waves x 16 sensors; grid (36 sensor-blocks, 16 bins, SPLIT).
// ---------------------------------------------------------------------------
__global__ __launch_bounds__(256) void k_main(
    const _Float16* __restrict__ bfrag, const float2* __restrict__ posc,
    const int* __restrict__ cnt, const float* __restrict__ el_spread,
    const float* __restrict__ sensors, float* __restrict__ part)
{
    int tid = threadIdx.x;
    int wv = tid >> 6, lane = tid & 63;
    int sb = blockIdx.x, bin = blockIdx.y, split = blockIdx.z;
    int quad = lane >> 4;

    int sA = sb * 64 + wv * 16 + (lane & 15);    // A-operand sensor (m = lane&15)
    float sxA = sensors[2 * sA], syA = sensors[2 * sA + 1];
    float es = el_spread[0];
    float CL = (-0.5f / (es * es)) * 1.4426950408889634f;  // fold log2(e)

    int count = min(cnt[bin], RCAP);
    int nch = (count + 31) >> 5;
    int c0 = nch * split / SPLIT, c1 = nch * (split + 1) / SPLIT;

    floatx4 d0 = {0.f, 0.f, 0.f, 0.f}, d1 = {0.f, 0.f, 0.f, 0.f};

    for (int c = c0; c < c1; ++c) {
        const half8* bb = (const half8*)bfrag +
                          ((size_t)(bin * CCAP + c)) * 4 * 64 + lane;
        half8 bh0 = bb[0];
        half8 bh1 = bb[64];
        half8 bl0 = bb[128];
        half8 bl1 = bb[192];

        const float4* pp = (const float4*)(posc +
                           ((size_t)bin * RCAP + c * 32 + quad * 8));
        float4 p0 = pp[0], p1 = pp[1], p2 = pp[2], p3 = pp[3];
        float exs[8] = {p0.x, p0.z, p1.x, p1.z, p2.x, p2.z, p3.x, p3.z};
        float eys[8] = {p0.y, p0.w, p1.y, p1.w, p2.y, p2.w, p3.y, p3.w};

        half8 ah, al;
#pragma unroll
        for (int j = 0; j < 8; ++j) {
            float dx = sxA - exs[j], dy = syA - eys[j];
            float d2 = fmaf(dx, dx, dy * dy);
            float e = exp2f(d2 * CL);
            _Float16 h = (_Float16)e;
            ah[j] = h;
            al[j] = (_Float16)(e - (float)h);
        }
        d0 = __builtin_amdgcn_mfma_f32_16x16x32_f16(ah, bh0, d0, 0, 0, 0);
        d1 = __builtin_amdgcn_mfma_f32_16x16x32_f16(ah, bh1, d1, 0, 0, 0);
        d0 = __builtin_amdgcn_mfma_f32_16x16x32_f16(al, bh0, d0, 0, 0, 0);
        d1 = __builtin_amdgcn_mfma_f32_16x16x32_f16(al, bh1, d1, 0, 0, 0);
        d0 = __builtin_amdgcn_mfma_f32_16x16x32_f16(ah, bl0, d0, 0, 0, 0);
        d1 = __builtin_amdgcn_mfma_f32_16x16x32_f16(ah, bl1, d1, 0, 0, 0);
    }

    // D layout: row m = quad*4 + r (sensor), col = lane&15 (tick in ntile)
    float* pb = part + (((size_t)split * NSB + sb) * NBINS + bin) * 2048;
    int n0 = lane & 15;
#pragma unroll
    for (int r = 0; r < 4; ++r) {
        int sl = wv * 16 + quad * 4 + r;
        pb[sl * 32 + n0]      = d0[r];
        pb[sl * 32 + 16 + n0] = d1[r];
    }
}

// ---------------------------------------------------------------------------
// Kernel 4: reduce split-K partials into output (covers every element).
// ---------------------------------------------------------------------------
__global__ __launch_bounds__(256) void k_reduce(
    const float4* __restrict__ part, float* __restrict__ out)
{
    int sb = blockIdx.x, bin = blockIdx.y, tid = threadIdx.x;
#pragma unroll
    for (int h = 0; h < 2; ++h) {
        int p = h * 256 + tid;            // float4 index within 512
        int sl = p >> 3, q = p & 7;
        float4 s = make_float4(0.f, 0.f, 0.f, 0.f);
        for (int sp = 0; sp < SPLIT; ++sp) {
            float4 v = part[(((size_t)sp * NSB + sb) * NBINS + bin) * 512 + p];
            s.x += v.x; s.y += v.y; s.z += v.z; s.w += v.w;
        }
        int sensor = sb * 64 + sl;
        *(float4*)(out + (size_t)sensor * Tg + bin * TT + q * 4) = s;
    }
}

// ---------------------------------------------------------------------------
extern "C" void kernel_launch(void* const* d_in, const int* in_sizes, int n_in,
                              void* d_out, int out_size, void* d_ws, size_t ws_size,
                              hipStream_t stream)
{
    const float* sim       = (const float*)d_in[0];
    const float* zpos      = (const float*)d_in[1];
    const float* mask      = (const float*)d_in[2];
    const float* W1        = (const float*)d_in[3];
    const float* b1        = (const float*)d_in[4];
    const float* W2        = (const float*)d_in[5];
    const float* b2        = (const float*)d_in[6];
    const float* W3        = (const float*)d_in[7];
    const float* b3        = (const float*)d_in[8];
    const float* el_spread = (const float*)d_in[9];
    const float* sensors   = (const float*)d_in[10];
    float* out = (float*)d_out;

    char* ws = (char*)d_ws;
    _Float16* bfrag = (_Float16*)(ws + OFF_BFRAG);
    float2*   posc  = (float2*)(ws + OFF_POSC);
    float*    part  = (float*)(ws + OFF_PART);
    float*    resp8 = (float*)(ws + OFF_RESP8);
    float4*   edata = (float4*)(ws + OFF_EDATA);
    int*      list  = (int*)(ws + OFF_LIST);
    int*      cnt   = (int*)(ws + OFF_CNT);

    hipMemsetAsync(cnt, 0, NBINS * sizeof(int), stream);

    k_electron<<<dim3((NG + 255) / 256, KSPLIT), 256, 0, stream>>>(
        sim, zpos, mask, W1, b1, W2, b2, W3, b3, edata, resp8, cnt, list);

    k_prof<<<dim3(RCAP / 8, NBINS), 256, 0, stream>>>(
        edata, resp8, cnt, list, el_spread, bfrag, posc);

    k_main<<<dim3(NSB, NBINS, SPLIT), 256, 0, stream>>>(
        bfrag, posc, cnt, el_spread, sensors, part);

    k_reduce<<<dim3(NSB, NBINS), 256, 0, stream>>>((const float4*)part, out);
}

// Round 5
// 239.071 us; speedup vs baseline: 1.6421x; 1.0653x over previous
//
#include <hip/hip_runtime.h>
#include <math.h>

// Problem constants
#define NXg 48
#define NYg 48
#define Tg 512
#define NG 20000              // B*NE, batch folded
#define H1g 64
#define H2g 128

// Tiling
#define TT 32                 // ticks per bin
#define NBINS 16
#define RCAP 3072             // per-bin list capacity (max count ~2650)
#define CCAP (RCAP / 32)      // 96 K-chunks max per bin
#define SPLIT 3               // split-K over chunks
#define KSPLIT 8              // k_electron H2 split
#define NSB 36                // sensor blocks of 64 (36*64 = 2304)
#define E2 2                  // electrons per thread in k_electron
#define EB 128                // k_electron block size

typedef float vf16 __attribute__((ext_vector_type(16)));
typedef _Float16 half8 __attribute__((ext_vector_type(8)));
typedef float floatx4 __attribute__((ext_vector_type(4)));

// ws layout (bytes)
#define OFF_BFRAG 0                                   //  6,291,456 (16*96*4*512 f16)
#define OFF_POSC  (OFF_BFRAG + (size_t)NBINS*CCAP*4*512*2)
#define OFF_PART  (OFF_POSC  + (size_t)NBINS*RCAP*8)  // 14,155,776
#define OFF_RESP8 (OFF_PART  + (size_t)SPLIT*NSB*NBINS*2048*4)
#define OFF_EDATA (OFF_RESP8 + (size_t)NG*8*4)
#define OFF_LIST  (OFF_EDATA + (size_t)NG*16)
#define OFF_CNT   (OFF_LIST  + (size_t)NBINS*RCAP*4)
// total ~22 MB

// ---------------------------------------------------------------------------
// Kernel 1: per-electron MLP partials (H2 split 8-way) + per-bin lists.
// W2 chunk staged in LDS (broadcast ds_read), 2 electrons/thread, h1 computed
// on the fly (no 64-reg array, no SMEM latency chain).
// ---------------------------------------------------------------------------
__global__ __launch_bounds__(EB) void k_electron(
    const float* __restrict__ sim, const float* __restrict__ zpos,
    const float* __restrict__ mask,
    const float* __restrict__ W1, const float* __restrict__ b1,
    const float* __restrict__ W2, const float* __restrict__ b2,
    const float* __restrict__ W3, const float* __restrict__ b3,
    float4* __restrict__ edata, float* __restrict__ resp8,
    int* __restrict__ cnt, int* __restrict__ list)
{
    __shared__ __align__(64) float sW2[H1g][16];   // this block's 16-col chunk
    __shared__ float4 sW1b[H1g];                   // {W1[j], W1[64+j], b1[j], 0}

    int tid = threadIdx.x;
    int q = blockIdx.y;                  // H2 chunk 0..7
    int k0 = q * 16;

    if (tid < H1g)
        sW1b[tid] = make_float4(W1[tid], W1[H1g + tid], b1[tid], 0.0f);
    for (int idx = tid; idx < 256; idx += EB) {
        int j = idx >> 2, c = (idx & 3) * 4;
        *(float4*)&sW2[j][c] = *(const float4*)&W2[j * H2g + k0 + c];
    }
    __syncthreads();

    int g0 = blockIdx.x * EB + tid;
    if (g0 >= NG / E2) return;
    int g1 = g0 + NG / E2;

    float2 s0 = *(const float2*)&sim[2 * g0];
    float2 s1 = *(const float2*)&sim[2 * g1];

    vf16 a0 = *(const vf16*)&b2[k0];     // uniform, one-time
    vf16 a1 = a0;
#pragma unroll 4
    for (int j = 0; j < H1g; ++j) {
        float4 wb = sW1b[j];             // LDS broadcast
        float h0 = fmaxf(fmaf(s0.x, wb.x, fmaf(s0.y, wb.y, wb.z)), 0.0f);
        float h1 = fmaxf(fmaf(s1.x, wb.x, fmaf(s1.y, wb.y, wb.z)), 0.0f);
        vf16 w = *(const vf16*)sW2[j];   // LDS broadcast, 64B
#pragma unroll
        for (int u = 0; u < 16; ++u) {
            a0[u] = fmaf(h0, w[u], a0[u]);
            a1[u] = fmaf(h1, w[u], a1[u]);
        }
    }

    float r0 = (q == 0) ? b3[0] : 0.0f;
    float r1 = r0;
#pragma unroll
    for (int u = 0; u < 16; ++u) {
        float w3 = W3[k0 + u];           // uniform, one-time
        r0 = fmaf(fmaxf(a0[u], 0.0f), w3, r0);
        r1 = fmaf(fmaxf(a1[u], 0.0f), w3, r1);
    }
    resp8[g0 * 8 + q] = r0;
    resp8[g1 * 8 + q] = r1;

    if (q == 0) {
        float z0 = zpos[g0], z1 = zpos[g1];
        edata[g0] = make_float4(s0.x, s0.y, z0, mask[g0]);
        edata[g1] = make_float4(s1.x, s1.y, z1, mask[g1]);
        // bins with min |t-z| <= sqrt(180): dropped time terms < e^-18
#pragma unroll
        for (int e = 0; e < 2; ++e) {
            float z = e ? z1 : z0;
            int g = e ? g1 : g0;
            int jlo = (int)ceilf((z - 44.5f) * (1.0f / 32.0f));
            int jhi = (int)floorf((z + 13.5f) * (1.0f / 32.0f));
            jlo = max(jlo, 0);
            jhi = min(jhi, NBINS - 1);
            for (int j = jlo; j <= jhi; ++j) {
                int p = atomicAdd(&cnt[j], 1);
                if (p < RCAP) list[j * RCAP + p] = g;
            }
        }
    }
}

// ---------------------------------------------------------------------------
// Kernel 2: build MFMA B-fragments (split-2 f16 hi/lo, amp-folded time
// profiles) pre-packed in per-lane fragment order, + chunk-padded positions.
// 16 threads per list entry (2 ticks each); resp partial-sum via shfl_xor.
// ---------------------------------------------------------------------------
__global__ __launch_bounds__(256) void k_prof(
    const float4* __restrict__ edata, const float* __restrict__ resp8,
    const int* __restrict__ cnt, const int* __restrict__ list,
    const float* __restrict__ el_spread,
    _Float16* __restrict__ bfrag, float2* __restrict__ posc)
{
    int bin = blockIdx.y;
    int tid = threadIdx.x;
    int i = blockIdx.x * 16 + (tid >> 4);     // list position
    int t16 = tid & 15;
    int count = min(cnt[bin], RCAP);
    int npad = (count + 31) & ~31;
    if (i >= npad) return;

    int ch = i >> 5, kl = i & 31;
    int quad = kl >> 3, jj = kl & 7;
    int lane = quad * 16 + t16;
    size_t base = ((size_t)(bin * CCAP + ch)) * 4 * 512;   // f16 units

    if (i < count) {
        int g = list[bin * RCAP + i];
        float4 E = edata[g];
        float rv = resp8[g * 8 + (tid & 7)];  // 8 partials across aligned 8-group
        rv += __shfl_xor(rv, 1);
        rv += __shfl_xor(rv, 2);
        rv += __shfl_xor(rv, 4);              // every lane: full resp sum
        float es = el_spread[0];
        float amp = rv * E.w * (100.0f / (es * 2.5066f)) *
                    (0.3989422804f / 2.23606797749979f);
#pragma unroll
        for (int nt = 0; nt < 2; ++nt) {
            float d = (float)(bin * TT + nt * 16 + t16) - E.z;
            float v = amp * __expf(-0.1f * d * d);
            _Float16 h = (_Float16)v;
            bfrag[base + (size_t)nt * 512 + lane * 8 + jj] = h;
            bfrag[base + (size_t)(2 + nt) * 512 + lane * 8 + jj] =
                (_Float16)(v - (float)h);
        }
        if (t16 == 0) posc[(size_t)bin * RCAP + i] = make_float2(E.x, E.y);
    } else {
#pragma unroll
        for (int nt = 0; nt < 2; ++nt) {
            bfrag[base + (size_t)nt * 512 + lane * 8 + jj] = (_Float16)0.0f;
            bfrag[base + (size_t)(2 + nt) * 512 + lane * 8 + jj] = (_Float16)0.0f;
        }
        if (t16 == 0) posc[(size_t)bin * RCAP + i] = make_float2(1.0e3f, 1.0e3f);
        // far pos -> exp underflows to 0, no NaN; B already zero
    }
}

// ---------------------------------------------------------------------------
// Kernel 3: MFMA main loop (unchanged from R4 — verified correct).
// Per bin: C[2304 x 32] += A[2304 x K] * B[K x 32]; split-2 f16.
// ---------------------------------------------------------------------------
__global__ __launch_bounds__(256) void k_main(
    const _Float16* __restrict__ bfrag, const float2* __restrict__ posc,
    const int* __restrict__ cnt, const float* __restrict__ el_spread,
    const float* __restrict__ sensors, float* __restrict__ part)
{
    int tid = threadIdx.x;
    int wv = tid >> 6, lane = tid & 63;
    int sb = blockIdx.x, bin = blockIdx.y, split = blockIdx.z;
    int quad = lane >> 4;

    int sA = sb * 64 + wv * 16 + (lane & 15);
    float sxA = sensors[2 * sA], syA = sensors[2 * sA + 1];
    float es = el_spread[0];
    float CL = (-0.5f / (es * es)) * 1.4426950408889634f;

    int count = min(cnt[bin], RCAP);
    int nch = (count + 31) >> 5;
    int c0 = nch * split / SPLIT, c1 = nch * (split + 1) / SPLIT;

    floatx4 d0 = {0.f, 0.f, 0.f, 0.f}, d1 = {0.f, 0.f, 0.f, 0.f};

    for (int c = c0; c < c1; ++c) {
        const half8* bb = (const half8*)bfrag +
                          ((size_t)(bin * CCAP + c)) * 4 * 64 + lane;
        half8 bh0 = bb[0];
        half8 bh1 = bb[64];
        half8 bl0 = bb[128];
        half8 bl1 = bb[192];

        const float4* pp = (const float4*)(posc +
                           ((size_t)bin * RCAP + c * 32 + quad * 8));
        float4 p0 = pp[0], p1 = pp[1], p2 = pp[2], p3 = pp[3];
        float exs[8] = {p0.x, p0.z, p1.x, p1.z, p2.x, p2.z, p3.x, p3.z};
        float eys[8] = {p0.y, p0.w, p1.y, p1.w, p2.y, p2.w, p3.y, p3.w};

        half8 ah, al;
#pragma unroll
        for (int j = 0; j < 8; ++j) {
            float dx = sxA - exs[j], dy = syA - eys[j];
            float d2 = fmaf(dx, dx, dy * dy);
            float e = exp2f(d2 * CL);
            _Float16 h = (_Float16)e;
            ah[j] = h;
            al[j] = (_Float16)(e - (float)h);
        }
        d0 = __builtin_amdgcn_mfma_f32_16x16x32_f16(ah, bh0, d0, 0, 0, 0);
        d1 = __builtin_amdgcn_mfma_f32_16x16x32_f16(ah, bh1, d1, 0, 0, 0);
        d0 = __builtin_amdgcn_mfma_f32_16x16x32_f16(al, bh0, d0, 0, 0, 0);
        d1 = __builtin_amdgcn_mfma_f32_16x16x32_f16(al, bh1, d1, 0, 0, 0);
        d0 = __builtin_amdgcn_mfma_f32_16x16x32_f16(ah, bl0, d0, 0, 0, 0);
        d1 = __builtin_amdgcn_mfma_f32_16x16x32_f16(ah, bl1, d1, 0, 0, 0);
    }

    float* pb = part + (((size_t)split * NSB + sb) * NBINS + bin) * 2048;
    int n0 = lane & 15;
#pragma unroll
    for (int r = 0; r < 4; ++r) {
        int sl = wv * 16 + quad * 4 + r;
        pb[sl * 32 + n0]      = d0[r];
        pb[sl * 32 + 16 + n0] = d1[r];
    }
}

// ---------------------------------------------------------------------------
// Kernel 4: reduce split-K partials into output (covers every element).
// ---------------------------------------------------------------------------
__global__ __launch_bounds__(256) void k_reduce(
    const float4* __restrict__ part, float* __restrict__ out)
{
    int sb = blockIdx.x, bin = blockIdx.y, tid = threadIdx.x;
#pragma unroll
    for (int h = 0; h < 2; ++h) {
        int p = h * 256 + tid;
        int sl = p >> 3, q = p & 7;
        float4 s = make_float4(0.f, 0.f, 0.f, 0.f);
        for (int sp = 0; sp < SPLIT; ++sp) {
            float4 v = part[(((size_t)sp * NSB + sb) * NBINS + bin) * 512 + p];
            s.x += v.x; s.y += v.y; s.z += v.z; s.w += v.w;
        }
        int sensor = sb * 64 + sl;
        *(float4*)(out + (size_t)sensor * Tg + bin * TT + q * 4) = s;
    }
}

// ---------------------------------------------------------------------------
extern "C" void kernel_launch(void* const* d_in, const int* in_sizes, int n_in,
                              void* d_out, int out_size, void* d_ws, size_t ws_size,
                              hipStream_t stream)
{
    const float* sim       = (const float*)d_in[0];
    const float* zpos      = (const float*)d_in[1];
    const float* mask      = (const float*)d_in[2];
    const float* W1        = (const float*)d_in[3];
    const float* b1        = (const float*)d_in[4];
    const float* W2        = (const float*)d_in[5];
    const float* b2        = (const float*)d_in[6];
    const float* W3        = (const float*)d_in[7];
    const float* b3        = (const float*)d_in[8];
    const float* el_spread = (const float*)d_in[9];
    const float* sensors   = (const float*)d_in[10];
    float* out = (float*)d_out;

    char* ws = (char*)d_ws;
    _Float16* bfrag = (_Float16*)(ws + OFF_BFRAG);
    float2*   posc  = (float2*)(ws + OFF_POSC);
    float*    part  = (float*)(ws + OFF_PART);
    float*    resp8 = (float*)(ws + OFF_RESP8);
    float4*   edata = (float4*)(ws + OFF_EDATA);
    int*      list  = (int*)(ws + OFF_LIST);
    int*      cnt   = (int*)(ws + OFF_CNT);

    hipMemsetAsync(cnt, 0, NBINS * sizeof(int), stream);

    k_electron<<<dim3((NG / E2 + EB - 1) / EB, KSPLIT), EB, 0, stream>>>(
        sim, zpos, mask, W1, b1, W2, b2, W3, b3, edata, resp8, cnt, list);

    k_prof<<<dim3(RCAP / 16, NBINS), 256, 0, stream>>>(
        edata, resp8, cnt, list, el_spread, bfrag, posc);

    k_main<<<dim3(NSB, NBINS, SPLIT), 256, 0, stream>>>(
        bfrag, posc, cnt, el_spread, sensors, part);

    k_reduce<<<dim3(NSB, NBINS), 256, 0, stream>>>((const float4*)part, out);
}

// Round 6
// 146.613 us; speedup vs baseline: 2.6776x; 1.6306x over previous
//
#include <hip/hip_runtime.h>
#include <math.h>

// Problem constants
#define NXg 48
#define NYg 48
#define Tg 512
#define NG 20000              // B*NE, batch folded
#define H1g 64
#define H2g 128

// Tiling
#define TT 32                 // ticks per bin
#define NBINS 16
#define RCAP 3072             // per-bin list capacity (max count ~2650)
#define CCAP (RCAP / 32)      // 96 K-chunks max per bin
#define SPLIT 3               // split-K over chunks
#define KSPLIT 8              // H2 split
#define NSB 36                // sensor blocks of 64 (36*64 = 2304)
#define E2 2                  // electrons per thread in k_mlp
#define EB 256                // k_mlp block size

typedef float vf16 __attribute__((ext_vector_type(16)));
typedef _Float16 half8 __attribute__((ext_vector_type(8)));
typedef float floatx4 __attribute__((ext_vector_type(4)));

// ws layout (bytes)
#define OFF_BFRAG 0                                   //  6,291,456 (16*96*4*512 f16)
#define OFF_POSC  (OFF_BFRAG + (size_t)NBINS*CCAP*4*512*2)
#define OFF_PART  (OFF_POSC  + (size_t)NBINS*RCAP*8)  // 14,155,776
#define OFF_RESP8 (OFF_PART  + (size_t)SPLIT*NSB*NBINS*2048*4)
#define OFF_EDATA (OFF_RESP8 + (size_t)NG*8*4)
#define OFF_LIST  (OFF_EDATA + (size_t)NG*16)
#define OFF_CNT   (OFF_LIST  + (size_t)NBINS*RCAP*4)
// total ~22 MB

// ---------------------------------------------------------------------------
// Kernel 1a: per-electron MLP partials (H2 split 8-way). Pure compute —
// no atomics. resp8 layout [q][g] -> coalesced stride-1 writes.
// ---------------------------------------------------------------------------
__global__ __launch_bounds__(EB) void k_mlp(
    const float* __restrict__ sim, const float* __restrict__ zpos,
    const float* __restrict__ mask,
    const float* __restrict__ W1, const float* __restrict__ b1,
    const float* __restrict__ W2, const float* __restrict__ b2,
    const float* __restrict__ W3, const float* __restrict__ b3,
    float4* __restrict__ edata, float* __restrict__ resp8)
{
    __shared__ __align__(64) float sW2[H1g][16];   // this block's 16-col chunk
    __shared__ float4 sW1b[H1g];                   // {W1[j], W1[64+j], b1[j], 0}

    int tid = threadIdx.x;
    int q = blockIdx.y;                  // H2 chunk 0..7
    int k0 = q * 16;

    if (tid < H1g)
        sW1b[tid] = make_float4(W1[tid], W1[H1g + tid], b1[tid], 0.0f);
    if (tid < 256) {
        int j = tid >> 2, c = (tid & 3) * 4;
        *(float4*)&sW2[j][c] = *(const float4*)&W2[j * H2g + k0 + c];
    }
    __syncthreads();

    int g0 = blockIdx.x * EB + tid;
    if (g0 >= NG / E2) return;
    int g1 = g0 + NG / E2;

    float2 s0 = *(const float2*)&sim[2 * g0];
    float2 s1 = *(const float2*)&sim[2 * g1];

    vf16 a0 = *(const vf16*)&b2[k0];     // uniform, one-time
    vf16 a1 = a0;
#pragma unroll 4
    for (int j = 0; j < H1g; ++j) {
        float4 wb = sW1b[j];             // LDS broadcast
        float h0 = fmaxf(fmaf(s0.x, wb.x, fmaf(s0.y, wb.y, wb.z)), 0.0f);
        float h1 = fmaxf(fmaf(s1.x, wb.x, fmaf(s1.y, wb.y, wb.z)), 0.0f);
        vf16 w = *(const vf16*)sW2[j];   // LDS broadcast, 64B
#pragma unroll
        for (int u = 0; u < 16; ++u) {
            a0[u] = fmaf(h0, w[u], a0[u]);
            a1[u] = fmaf(h1, w[u], a1[u]);
        }
    }

    float r0 = (q == 0) ? b3[0] : 0.0f;
    float r1 = r0;
#pragma unroll
    for (int u = 0; u < 16; ++u) {
        float w3 = W3[k0 + u];           // uniform, one-time
        r0 = fmaf(fmaxf(a0[u], 0.0f), w3, r0);
        r1 = fmaf(fmaxf(a1[u], 0.0f), w3, r1);
    }
    resp8[(size_t)q * NG + g0] = r0;     // coalesced
    resp8[(size_t)q * NG + g1] = r1;

    if (q == 0) {
        edata[g0] = make_float4(s0.x, s0.y, zpos[g0], mask[g0]);
        edata[g1] = make_float4(s1.x, s1.y, zpos[g1], mask[g1]);
    }
}

// ---------------------------------------------------------------------------
// Kernel 1b: two-phase binning. LDS histogram per block (fast LDS atomics),
// one global atomicAdd per (block,bin) to reserve ranges, then scatter.
// ---------------------------------------------------------------------------
__global__ __launch_bounds__(256) void k_bins(
    const float* __restrict__ zpos, int* __restrict__ cnt, int* __restrict__ list)
{
    __shared__ int lcnt[NBINS], lbase[NBINS];
    int tid = threadIdx.x;
    if (tid < NBINS) lcnt[tid] = 0;
    __syncthreads();

    int g = blockIdx.x * 256 + tid;
    int jlo = 0, jhi = -1;
    int off[3];                          // window 58 ticks -> at most 3 bins
    if (g < NG) {
        float z = zpos[g];
        // bins with min |t-z| <= sqrt(180): dropped time terms < e^-18
        jlo = max((int)ceilf((z - 44.5f) * (1.0f / 32.0f)), 0);
        jhi = min((int)floorf((z + 13.5f) * (1.0f / 32.0f)), NBINS - 1);
        for (int j = jlo; j <= jhi; ++j)
            off[j - jlo] = atomicAdd(&lcnt[j], 1);
    }
    __syncthreads();
    if (tid < NBINS) {
        int c = lcnt[tid];
        lbase[tid] = c ? atomicAdd(&cnt[tid], c) : 0;
    }
    __syncthreads();
    for (int j = jlo; j <= jhi; ++j) {
        int p = lbase[j] + off[j - jlo];
        if (p < RCAP) list[j * RCAP + p] = g;
    }
}

// ---------------------------------------------------------------------------
// Kernel 2: build MFMA B-fragments (split-2 f16 hi/lo, amp-folded time
// profiles) pre-packed in per-lane fragment order, + chunk-padded positions.
// 16 threads per list entry (2 ticks each); resp partial-sum via shfl_xor.
// ---------------------------------------------------------------------------
__global__ __launch_bounds__(256) void k_prof(
    const float4* __restrict__ edata, const float* __restrict__ resp8,
    const int* __restrict__ cnt, const int* __restrict__ list,
    const float* __restrict__ el_spread,
    _Float16* __restrict__ bfrag, float2* __restrict__ posc)
{
    int bin = blockIdx.y;
    int tid = threadIdx.x;
    int i = blockIdx.x * 16 + (tid >> 4);     // list position
    int t16 = tid & 15;
    int count = min(cnt[bin], RCAP);
    int npad = (count + 31) & ~31;
    if (i >= npad) return;

    int ch = i >> 5, kl = i & 31;
    int quad = kl >> 3, jj = kl & 7;
    int lane = quad * 16 + t16;
    size_t base = ((size_t)(bin * CCAP + ch)) * 4 * 512;   // f16 units

    if (i < count) {
        int g = list[bin * RCAP + i];
        float4 E = edata[g];
        float rv = resp8[(size_t)(tid & 7) * NG + g];  // 8 partials per 8-group
        rv += __shfl_xor(rv, 1);
        rv += __shfl_xor(rv, 2);
        rv += __shfl_xor(rv, 4);              // every lane: full resp sum
        float es = el_spread[0];
        float amp = rv * E.w * (100.0f / (es * 2.5066f)) *
                    (0.3989422804f / 2.23606797749979f);
#pragma unroll
        for (int nt = 0; nt < 2; ++nt) {
            float d = (float)(bin * TT + nt * 16 + t16) - E.z;
            float v = amp * __expf(-0.1f * d * d);
            _Float16 h = (_Float16)v;
            bfrag[base + (size_t)nt * 512 + lane * 8 + jj] = h;
            bfrag[base + (size_t)(2 + nt) * 512 + lane * 8 + jj] =
                (_Float16)(v - (float)h);
        }
        if (t16 == 0) posc[(size_t)bin * RCAP + i] = make_float2(E.x, E.y);
    } else {
#pragma unroll
        for (int nt = 0; nt < 2; ++nt) {
            bfrag[base + (size_t)nt * 512 + lane * 8 + jj] = (_Float16)0.0f;
            bfrag[base + (size_t)(2 + nt) * 512 + lane * 8 + jj] = (_Float16)0.0f;
        }
        if (t16 == 0) posc[(size_t)bin * RCAP + i] = make_float2(1.0e3f, 1.0e3f);
        // far pos -> exp underflows to 0, no NaN; B already zero
    }
}

// ---------------------------------------------------------------------------
// Kernel 3: MFMA main loop (unchanged — verified correct).
// Per bin: C[2304 x 32] += A[2304 x K] * B[K x 32]; split-2 f16.
// ---------------------------------------------------------------------------
__global__ __launch_bounds__(256) void k_main(
    const _Float16* __restrict__ bfrag, const float2* __restrict__ posc,
    const int* __restrict__ cnt, const float* __restrict__ el_spread,
    const float* __restrict__ sensors, float* __restrict__ part)
{
    int tid = threadIdx.x;
    int wv = tid >> 6, lane = tid & 63;
    int sb = blockIdx.x, bin = blockIdx.y, split = blockIdx.z;
    int quad = lane >> 4;

    int sA = sb * 64 + wv * 16 + (lane & 15);
    float sxA = sensors[2 * sA], syA = sensors[2 * sA + 1];
    float es = el_spread[0];
    float CL = (-0.5f / (es * es)) * 1.4426950408889634f;

    int count = min(cnt[bin], RCAP);
    int nch = (count + 31) >> 5;
    int c0 = nch * split / SPLIT, c1 = nch * (split + 1) / SPLIT;

    floatx4 d0 = {0.f, 0.f, 0.f, 0.f}, d1 = {0.f, 0.f, 0.f, 0.f};

    for (int c = c0; c < c1; ++c) {
        const half8* bb = (const half8*)bfrag +
                          ((size_t)(bin * CCAP + c)) * 4 * 64 + lane;
        half8 bh0 = bb[0];
        half8 bh1 = bb[64];
        half8 bl0 = bb[128];
        half8 bl1 = bb[192];

        const float4* pp = (const float4*)(posc +
                           ((size_t)bin * RCAP + c * 32 + quad * 8));
        float4 p0 = pp[0], p1 = pp[1], p2 = pp[2], p3 = pp[3];
        float exs[8] = {p0.x, p0.z, p1.x, p1.z, p2.x, p2.z, p3.x, p3.z};
        float eys[8] = {p0.y, p0.w, p1.y, p1.w, p2.y, p2.w, p3.y, p3.w};

        half8 ah, al;
#pragma unroll
        for (int j = 0; j < 8; ++j) {
            float dx = sxA - exs[j], dy = syA - eys[j];
            float d2 = fmaf(dx, dx, dy * dy);
            float e = exp2f(d2 * CL);
            _Float16 h = (_Float16)e;
            ah[j] = h;
            al[j] = (_Float16)(e - (float)h);
        }
        d0 = __builtin_amdgcn_mfma_f32_16x16x32_f16(ah, bh0, d0, 0, 0, 0);
        d1 = __builtin_amdgcn_mfma_f32_16x16x32_f16(ah, bh1, d1, 0, 0, 0);
        d0 = __builtin_amdgcn_mfma_f32_16x16x32_f16(al, bh0, d0, 0, 0, 0);
        d1 = __builtin_amdgcn_mfma_f32_16x16x32_f16(al, bh1, d1, 0, 0, 0);
        d0 = __builtin_amdgcn_mfma_f32_16x16x32_f16(ah, bl0, d0, 0, 0, 0);
        d1 = __builtin_amdgcn_mfma_f32_16x16x32_f16(ah, bl1, d1, 0, 0, 0);
    }

    float* pb = part + (((size_t)split * NSB + sb) * NBINS + bin) * 2048;
    int n0 = lane & 15;
#pragma unroll
    for (int r = 0; r < 4; ++r) {
        int sl = wv * 16 + quad * 4 + r;
        pb[sl * 32 + n0]      = d0[r];
        pb[sl * 32 + 16 + n0] = d1[r];
    }
}

// ---------------------------------------------------------------------------
// Kernel 4: reduce split-K partials into output (covers every element).
// ---------------------------------------------------------------------------
__global__ __launch_bounds__(256) void k_reduce(
    const float4* __restrict__ part, float* __restrict__ out)
{
    int sb = blockIdx.x, bin = blockIdx.y, tid = threadIdx.x;
#pragma unroll
    for (int h = 0; h < 2; ++h) {
        int p = h * 256 + tid;
        int sl = p >> 3, q = p & 7;
        float4 s = make_float4(0.f, 0.f, 0.f, 0.f);
        for (int sp = 0; sp < SPLIT; ++sp) {
            float4 v = part[(((size_t)sp * NSB + sb) * NBINS + bin) * 512 + p];
            s.x += v.x; s.y += v.y; s.z += v.z; s.w += v.w;
        }
        int sensor = sb * 64 + sl;
        *(float4*)(out + (size_t)sensor * Tg + bin * TT + q * 4) = s;
    }
}

// ---------------------------------------------------------------------------
extern "C" void kernel_launch(void* const* d_in, const int* in_sizes, int n_in,
                              void* d_out, int out_size, void* d_ws, size_t ws_size,
                              hipStream_t stream)
{
    const float* sim       = (const float*)d_in[0];
    const float* zpos      = (const float*)d_in[1];
    const float* mask      = (const float*)d_in[2];
    const float* W1        = (const float*)d_in[3];
    const float* b1        = (const float*)d_in[4];
    const float* W2        = (const float*)d_in[5];
    const float* b2        = (const float*)d_in[6];
    const float* W3        = (const float*)d_in[7];
    const float* b3        = (const float*)d_in[8];
    const float* el_spread = (const float*)d_in[9];
    const float* sensors   = (const float*)d_in[10];
    float* out = (float*)d_out;

    char* ws = (char*)d_ws;
    _Float16* bfrag = (_Float16*)(ws + OFF_BFRAG);
    float2*   posc  = (float2*)(ws + OFF_POSC);
    float*    part  = (float*)(ws + OFF_PART);
    float*    resp8 = (float*)(ws + OFF_RESP8);
    float4*   edata = (float4*)(ws + OFF_EDATA);
    int*      list  = (int*)(ws + OFF_LIST);
    int*      cnt   = (int*)(ws + OFF_CNT);

    hipMemsetAsync(cnt, 0, NBINS * sizeof(int), stream);

    k_mlp<<<dim3((NG / E2 + EB - 1) / EB, KSPLIT), EB, 0, stream>>>(
        sim, zpos, mask, W1, b1, W2, b2, W3, b3, edata, resp8);

    k_bins<<<(NG + 255) / 256, 256, 0, stream>>>(zpos, cnt, list);

    k_prof<<<dim3(RCAP / 16, NBINS), 256, 0, stream>>>(
        edata, resp8, cnt, list, el_spread, bfrag, posc);

    k_main<<<dim3(NSB, NBINS, SPLIT), 256, 0, stream>>>(
        bfrag, posc, cnt, el_spread, sensors, part);

    k_reduce<<<dim3(NSB, NBINS), 256, 0, stream>>>((const float4*)part, out);
}

// Round 7
// 145.563 us; speedup vs baseline: 2.6969x; 1.0072x over previous
//
#include <hip/hip_runtime.h>
#include <math.h>

// Problem constants
#define NXg 48
#define NYg 48
#define Tg 512
#define NG 20000              // B*NE, batch folded
#define H1g 64
#define H2g 128

// Tiling
#define TT 32                 // ticks per bin
#define NBINS 16
#define RCAP 3072             // per-bin list capacity (max count ~2650)
#define CCAP (RCAP / 32)      // 96 K-chunks max per bin
#define SPLIT 3               // split-K over chunks
#define KSPLIT 8              // H2 split
#define NSB 36                // sensor blocks of 64 (36*64 = 2304)
#define E2 2                  // electrons per thread in k_mlp
#define EB 256                // k_mlp block size

typedef float vf16 __attribute__((ext_vector_type(16)));
typedef _Float16 half8 __attribute__((ext_vector_type(8)));
typedef float floatx4 __attribute__((ext_vector_type(4)));

// ws layout (bytes)
#define OFF_BFRAG  0                                    //  6,291,456
#define OFF_POSC   (OFF_BFRAG  + (size_t)NBINS*CCAP*4*512*2)
#define OFF_PART   (OFF_POSC   + (size_t)NBINS*RCAP*8)  // 14,155,776
#define OFF_RESP8  (OFF_PART   + (size_t)SPLIT*NSB*NBINS*2048*4)
#define OFF_EDATA  (OFF_RESP8  + (size_t)NG*8*4)
#define OFF_EDATA2 (OFF_EDATA  + (size_t)NG*16)
#define OFF_LIST   (OFF_EDATA2 + (size_t)NG*16)
#define OFF_CNT    (OFF_LIST   + (size_t)NBINS*RCAP*4)
// total ~22.3 MB

// ---------------------------------------------------------------------------
// Kernel 1a: per-electron MLP partials (H2 split 8-way). No atomics;
// resp8 layout [q][g] -> coalesced writes. (unchanged — verified)
// ---------------------------------------------------------------------------
__global__ __launch_bounds__(EB) void k_mlp(
    const float* __restrict__ sim, const float* __restrict__ zpos,
    const float* __restrict__ mask,
    const float* __restrict__ W1, const float* __restrict__ b1,
    const float* __restrict__ W2, const float* __restrict__ b2,
    const float* __restrict__ W3, const float* __restrict__ b3,
    float4* __restrict__ edata, float* __restrict__ resp8)
{
    __shared__ __align__(64) float sW2[H1g][16];
    __shared__ float4 sW1b[H1g];

    int tid = threadIdx.x;
    int q = blockIdx.y;
    int k0 = q * 16;

    if (tid < H1g)
        sW1b[tid] = make_float4(W1[tid], W1[H1g + tid], b1[tid], 0.0f);
    if (tid < 256) {
        int j = tid >> 2, c = (tid & 3) * 4;
        *(float4*)&sW2[j][c] = *(const float4*)&W2[j * H2g + k0 + c];
    }
    __syncthreads();

    int g0 = blockIdx.x * EB + tid;
    if (g0 >= NG / E2) return;
    int g1 = g0 + NG / E2;

    float2 s0 = *(const float2*)&sim[2 * g0];
    float2 s1 = *(const float2*)&sim[2 * g1];

    vf16 a0 = *(const vf16*)&b2[k0];
    vf16 a1 = a0;
#pragma unroll 4
    for (int j = 0; j < H1g; ++j) {
        float4 wb = sW1b[j];
        float h0 = fmaxf(fmaf(s0.x, wb.x, fmaf(s0.y, wb.y, wb.z)), 0.0f);
        float h1 = fmaxf(fmaf(s1.x, wb.x, fmaf(s1.y, wb.y, wb.z)), 0.0f);
        vf16 w = *(const vf16*)sW2[j];
#pragma unroll
        for (int u = 0; u < 16; ++u) {
            a0[u] = fmaf(h0, w[u], a0[u]);
            a1[u] = fmaf(h1, w[u], a1[u]);
        }
    }

    float r0 = (q == 0) ? b3[0] : 0.0f;
    float r1 = r0;
#pragma unroll
    for (int u = 0; u < 16; ++u) {
        float w3 = W3[k0 + u];
        r0 = fmaf(fmaxf(a0[u], 0.0f), w3, r0);
        r1 = fmaf(fmaxf(a1[u], 0.0f), w3, r1);
    }
    resp8[(size_t)q * NG + g0] = r0;
    resp8[(size_t)q * NG + g1] = r1;

    if (q == 0) {
        edata[g0] = make_float4(s0.x, s0.y, zpos[g0], mask[g0]);
        edata[g1] = make_float4(s1.x, s1.y, zpos[g1], mask[g1]);
    }
}

// ---------------------------------------------------------------------------
// Kernel 1b: two-phase binning (LDS histogram + one global reserve per
// block,bin). (unchanged — verified)
// ---------------------------------------------------------------------------
__global__ __launch_bounds__(256) void k_bins(
    const float* __restrict__ zpos, int* __restrict__ cnt, int* __restrict__ list)
{
    __shared__ int lcnt[NBINS], lbase[NBINS];
    int tid = threadIdx.x;
    if (tid < NBINS) lcnt[tid] = 0;
    __syncthreads();

    int g = blockIdx.x * 256 + tid;
    int jlo = 0, jhi = -1;
    int off[3];
    if (g < NG) {
        float z = zpos[g];
        jlo = max((int)ceilf((z - 44.5f) * (1.0f / 32.0f)), 0);
        jhi = min((int)floorf((z + 13.5f) * (1.0f / 32.0f)), NBINS - 1);
        for (int j = jlo; j <= jhi; ++j)
            off[j - jlo] = atomicAdd(&lcnt[j], 1);
    }
    __syncthreads();
    if (tid < NBINS) {
        int c = lcnt[tid];
        lbase[tid] = c ? atomicAdd(&cnt[tid], c) : 0;
    }
    __syncthreads();
    for (int j = jlo; j <= jhi; ++j) {
        int p = lbase[j] + off[j - jlo];
        if (p < RCAP) list[j * RCAP + p] = g;
    }
}

// ---------------------------------------------------------------------------
// Kernel 1c: fold resp partial-sums + mask + norms into per-electron amp.
// edata2 = (x, y, z, amp). Fully coalesced.
// ---------------------------------------------------------------------------
__global__ __launch_bounds__(256) void k_amp(
    const float4* __restrict__ edata, const float* __restrict__ resp8,
    const float* __restrict__ el_spread, float4* __restrict__ edata2)
{
    int g = blockIdx.x * 256 + threadIdx.x;
    if (g >= NG) return;
    float s = 0.0f;
#pragma unroll
    for (int q = 0; q < KSPLIT; ++q) s += resp8[(size_t)q * NG + g];
    float4 E = edata[g];
    float es = el_spread[0];
    float amp = s * E.w * (100.0f / (es * 2.5066f)) *
                (0.3989422804f / 2.23606797749979f);
    edata2[g] = make_float4(E.x, E.y, E.z, amp);
}

// ---------------------------------------------------------------------------
// Kernel 2: B-fragment build, coalesced. Thread = (chunk, nt, lane): computes
// 8 electrons' values at one tick, writes two contiguous half8 (16B) stores.
// Chunk electron data staged via LDS broadcast.
// ---------------------------------------------------------------------------
__global__ __launch_bounds__(256) void k_prof(
    const float4* __restrict__ edata2, const int* __restrict__ cnt,
    const int* __restrict__ list,
    _Float16* __restrict__ bfrag, float2* __restrict__ posc)
{
    __shared__ float4 sE[64];
    int bin = blockIdx.y;
    int tid = threadIdx.x;
    int count = min(cnt[bin], RCAP);
    int nch = (count + 31) >> 5;
    int cbase = blockIdx.x * 2;              // 2 chunks per block
    if (cbase >= nch) return;

    if (tid < 64) {
        int i = cbase * 32 + tid;            // entry index within bin
        float4 E = make_float4(1.0e3f, 1.0e3f, 0.0f, 0.0f);  // pad: amp=0, far pos
        if (i < count) E = edata2[list[bin * RCAP + i]];
        sE[tid] = E;
        if (i < nch * 32)
            posc[(size_t)bin * RCAP + i] = make_float2(E.x, E.y);
    }
    __syncthreads();

    int ch = cbase + (tid >> 7);
    if (ch >= nch) return;
    int nt = (tid >> 6) & 1;
    int lane = tid & 63;
    int quad = lane >> 4, t16 = lane & 15;
    float tt = (float)(bin * TT + nt * 16 + t16);

    half8 hi, lo;
#pragma unroll
    for (int j = 0; j < 8; ++j) {
        float4 E = sE[(tid >> 7) * 32 + quad * 8 + j];   // LDS broadcast
        float d = tt - E.z;
        float v = E.w * __expf(-0.1f * d * d);
        _Float16 h = (_Float16)v;
        hi[j] = h;
        lo[j] = (_Float16)(v - (float)h);
    }
    size_t base = ((size_t)(bin * CCAP + ch)) * 4 * 512;  // f16 units
    *(half8*)&bfrag[base + (size_t)nt * 512 + lane * 8] = hi;
    *(half8*)&bfrag[base + (size_t)(2 + nt) * 512 + lane * 8] = lo;
}

// ---------------------------------------------------------------------------
// Kernel 3: MFMA main loop. Per bin: C[2304 x 32] += A[2304 x K] * B[K x 32];
// split-2 f16. Only change vs R6: native __expf instead of libcall exp2f.
// ---------------------------------------------------------------------------
__global__ __launch_bounds__(256) void k_main(
    const _Float16* __restrict__ bfrag, const float2* __restrict__ posc,
    const int* __restrict__ cnt, const float* __restrict__ el_spread,
    const float* __restrict__ sensors, float* __restrict__ part)
{
    int tid = threadIdx.x;
    int wv = tid >> 6, lane = tid & 63;
    int sb = blockIdx.x, bin = blockIdx.y, split = blockIdx.z;
    int quad = lane >> 4;

    int sA = sb * 64 + wv * 16 + (lane & 15);
    float sxA = sensors[2 * sA], syA = sensors[2 * sA + 1];
    float es = el_spread[0];
    float CL = -0.5f / (es * es);            // natural-log domain

    int count = min(cnt[bin], RCAP);
    int nch = (count + 31) >> 5;
    int c0 = nch * split / SPLIT, c1 = nch * (split + 1) / SPLIT;

    floatx4 d0 = {0.f, 0.f, 0.f, 0.f}, d1 = {0.f, 0.f, 0.f, 0.f};

    for (int c = c0; c < c1; ++c) {
        const half8* bb = (const half8*)bfrag +
                          ((size_t)(bin * CCAP + c)) * 4 * 64 + lane;
        half8 bh0 = bb[0];
        half8 bh1 = bb[64];
        half8 bl0 = bb[128];
        half8 bl1 = bb[192];

        const float4* pp = (const float4*)(posc +
                           ((size_t)bin * RCAP + c * 32 + quad * 8));
        float4 p0 = pp[0], p1 = pp[1], p2 = pp[2], p3 = pp[3];
        float exs[8] = {p0.x, p0.z, p1.x, p1.z, p2.x, p2.z, p3.x, p3.z};
        float eys[8] = {p0.y, p0.w, p1.y, p1.w, p2.y, p2.w, p3.y, p3.w};

        half8 ah, al;
#pragma unroll
        for (int j = 0; j < 8; ++j) {
            float dx = sxA - exs[j], dy = syA - eys[j];
            float d2 = fmaf(dx, dx, dy * dy);
            float e = __expf(d2 * CL);       // native v_exp_f32
            _Float16 h = (_Float16)e;
            ah[j] = h;
            al[j] = (_Float16)(e - (float)h);
        }
        d0 = __builtin_amdgcn_mfma_f32_16x16x32_f16(ah, bh0, d0, 0, 0, 0);
        d1 = __builtin_amdgcn_mfma_f32_16x16x32_f16(ah, bh1, d1, 0, 0, 0);
        d0 = __builtin_amdgcn_mfma_f32_16x16x32_f16(al, bh0, d0, 0, 0, 0);
        d1 = __builtin_amdgcn_mfma_f32_16x16x32_f16(al, bh1, d1, 0, 0, 0);
        d0 = __builtin_amdgcn_mfma_f32_16x16x32_f16(ah, bl0, d0, 0, 0, 0);
        d1 = __builtin_amdgcn_mfma_f32_16x16x32_f16(ah, bl1, d1, 0, 0, 0);
    }

    float* pb = part + (((size_t)split * NSB + sb) * NBINS + bin) * 2048;
    int n0 = lane & 15;
#pragma unroll
    for (int r = 0; r < 4; ++r) {
        int sl = wv * 16 + quad * 4 + r;
        pb[sl * 32 + n0]      = d0[r];
        pb[sl * 32 + 16 + n0] = d1[r];
    }
}

// ---------------------------------------------------------------------------
// Kernel 4: reduce split-K partials into output. (unchanged — verified)
// ---------------------------------------------------------------------------
__global__ __launch_bounds__(256) void k_reduce(
    const float4* __restrict__ part, float* __restrict__ out)
{
    int sb = blockIdx.x, bin = blockIdx.y, tid = threadIdx.x;
#pragma unroll
    for (int h = 0; h < 2; ++h) {
        int p = h * 256 + tid;
        int sl = p >> 3, q = p & 7;
        float4 s = make_float4(0.f, 0.f, 0.f, 0.f);
        for (int sp = 0; sp < SPLIT; ++sp) {
            float4 v = part[(((size_t)sp * NSB + sb) * NBINS + bin) * 512 + p];
            s.x += v.x; s.y += v.y; s.z += v.z; s.w += v.w;
        }
        int sensor = sb * 64 + sl;
        *(float4*)(out + (size_t)sensor * Tg + bin * TT + q * 4) = s;
    }
}

// ---------------------------------------------------------------------------
extern "C" void kernel_launch(void* const* d_in, const int* in_sizes, int n_in,
                              void* d_out, int out_size, void* d_ws, size_t ws_size,
                              hipStream_t stream)
{
    const float* sim       = (const float*)d_in[0];
    const float* zpos      = (const float*)d_in[1];
    const float* mask      = (const float*)d_in[2];
    const float* W1        = (const float*)d_in[3];
    const float* b1        = (const float*)d_in[4];
    const float* W2        = (const float*)d_in[5];
    const float* b2        = (const float*)d_in[6];
    const float* W3        = (const float*)d_in[7];
    const float* b3        = (const float*)d_in[8];
    const float* el_spread = (const float*)d_in[9];
    const float* sensors   = (const float*)d_in[10];
    float* out = (float*)d_out;

    char* ws = (char*)d_ws;
    _Float16* bfrag  = (_Float16*)(ws + OFF_BFRAG);
    float2*   posc   = (float2*)(ws + OFF_POSC);
    float*    part   = (float*)(ws + OFF_PART);
    float*    resp8  = (float*)(ws + OFF_RESP8);
    float4*   edata  = (float4*)(ws + OFF_EDATA);
    float4*   edata2 = (float4*)(ws + OFF_EDATA2);
    int*      list   = (int*)(ws + OFF_LIST);
    int*      cnt    = (int*)(ws + OFF_CNT);

    hipMemsetAsync(cnt, 0, NBINS * sizeof(int), stream);

    k_mlp<<<dim3((NG / E2 + EB - 1) / EB, KSPLIT), EB, 0, stream>>>(
        sim, zpos, mask, W1, b1, W2, b2, W3, b3, edata, resp8);

    k_bins<<<(NG + 255) / 256, 256, 0, stream>>>(zpos, cnt, list);

    k_amp<<<(NG + 255) / 256, 256, 0, stream>>>(edata, resp8, el_spread, edata2);

    k_prof<<<dim3(CCAP / 2, NBINS), 256, 0, stream>>>(
        edata2, cnt, list, bfrag, posc);

    k_main<<<dim3(NSB, NBINS, SPLIT), 256, 0, stream>>>(
        bfrag, posc, cnt, el_spread, sensors, part);

    k_reduce<<<dim3(NSB, NBINS), 256, 0, stream>>>((const float4*)part, out);
}

// Round 9
// 140.867 us; speedup vs baseline: 2.7868x; 1.0333x over previous
//
#include <hip/hip_runtime.h>
#include <math.h>

// Problem constants
#define NXg 48
#define NYg 48
#define Tg 512
#define NG 20000              // B*NE, batch folded
#define H1g 64
#define H2g 128

// Tiling
#define TT 32                 // ticks per bin
#define NBINS 16
#define RCAP 3072             // per-bin list capacity (max count ~2650)
#define CCAP (RCAP / 32)      // 96 K-chunks max per bin
#define SPLIT 3               // split-K over chunks
#define KSPLIT 8              // H2 split
#define NSB 36                // sensor blocks of 64 (36*64 = 2304)
#define E2 2                  // electrons per thread in k_mlp
#define EB 256                // k_mlp block size

// coordinate pre-scale: exp(-0.5*d2/es^2) = exp2(-(k*d)^2), k = sqrt(0.5*log2 e)/es
#define KSCALE 0.84932180028802f

typedef float vf16 __attribute__((ext_vector_type(16)));
typedef _Float16 half8 __attribute__((ext_vector_type(8)));
typedef float floatx4 __attribute__((ext_vector_type(4)));

// ws layout (bytes)
#define OFF_BFRAG  0                                    //  6,291,456
#define OFF_POSC   (OFF_BFRAG  + (size_t)NBINS*CCAP*4*512*2)
#define OFF_PART   (OFF_POSC   + (size_t)NBINS*RCAP*8)  // 14,155,776
#define OFF_RESP8  (OFF_PART   + (size_t)SPLIT*NSB*NBINS*2048*4)
#define OFF_EDATA  (OFF_RESP8  + (size_t)NG*8*4)
#define OFF_EDATA2 (OFF_EDATA  + (size_t)NG*16)
#define OFF_LIST   (OFF_EDATA2 + (size_t)NG*16)
#define OFF_CNT    (OFF_LIST   + (size_t)NBINS*RCAP*4)
// total ~22.3 MB

// ---------------------------------------------------------------------------
// Kernel 1a: per-electron MLP partials (H2 split 8-way). Also zeroes cnt
// (block (0,0)) so no separate memset dispatch is needed.
// ---------------------------------------------------------------------------
__global__ __launch_bounds__(EB) void k_mlp(
    const float* __restrict__ sim, const float* __restrict__ zpos,
    const float* __restrict__ mask,
    const float* __restrict__ W1, const float* __restrict__ b1,
    const float* __restrict__ W2, const float* __restrict__ b2,
    const float* __restrict__ W3, const float* __restrict__ b3,
    float4* __restrict__ edata, float* __restrict__ resp8,
    int* __restrict__ cnt)
{
    __shared__ __align__(64) float sW2[H1g][16];
    __shared__ float4 sW1b[H1g];

    int tid = threadIdx.x;
    int q = blockIdx.y;
    int k0 = q * 16;

    if (blockIdx.x == 0 && q == 0 && tid < NBINS) cnt[tid] = 0;

    if (tid < H1g)
        sW1b[tid] = make_float4(W1[tid], W1[H1g + tid], b1[tid], 0.0f);
    if (tid < 256) {
        int j = tid >> 2, c = (tid & 3) * 4;
        *(float4*)&sW2[j][c] = *(const float4*)&W2[j * H2g + k0 + c];
    }
    __syncthreads();

    int g0 = blockIdx.x * EB + tid;
    if (g0 >= NG / E2) return;
    int g1 = g0 + NG / E2;

    float2 s0 = *(const float2*)&sim[2 * g0];
    float2 s1 = *(const float2*)&sim[2 * g1];

    vf16 a0 = *(const vf16*)&b2[k0];
    vf16 a1 = a0;
#pragma unroll 4
    for (int j = 0; j < H1g; ++j) {
        float4 wb = sW1b[j];
        float h0 = fmaxf(fmaf(s0.x, wb.x, fmaf(s0.y, wb.y, wb.z)), 0.0f);
        float h1 = fmaxf(fmaf(s1.x, wb.x, fmaf(s1.y, wb.y, wb.z)), 0.0f);
        vf16 w = *(const vf16*)sW2[j];
#pragma unroll
        for (int u = 0; u < 16; ++u) {
            a0[u] = fmaf(h0, w[u], a0[u]);
            a1[u] = fmaf(h1, w[u], a1[u]);
        }
    }

    float r0 = (q == 0) ? b3[0] : 0.0f;
    float r1 = r0;
#pragma unroll
    for (int u = 0; u < 16; ++u) {
        float w3 = W3[k0 + u];
        r0 = fmaf(fmaxf(a0[u], 0.0f), w3, r0);
        r1 = fmaf(fmaxf(a1[u], 0.0f), w3, r1);
    }
    resp8[(size_t)q * NG + g0] = r0;
    resp8[(size_t)q * NG + g1] = r1;

    if (q == 0) {
        edata[g0] = make_float4(s0.x, s0.y, zpos[g0], mask[g0]);
        edata[g1] = make_float4(s1.x, s1.y, zpos[g1], mask[g1]);
    }
}

// ---------------------------------------------------------------------------
// Kernel 1b: binning (LDS histogram + one global reserve per block,bin)
// fused with amp fold. edata2 = (x*k, y*k, z, amp), coords pre-scaled so
// the spatial gaussian is exp2(-(dx^2+dy^2)).
// ---------------------------------------------------------------------------
__global__ __launch_bounds__(256) void k_bins(
    const float4* __restrict__ edata, const float* __restrict__ resp8,
    const float* __restrict__ el_spread,
    int* __restrict__ cnt, int* __restrict__ list, float4* __restrict__ edata2)
{
    __shared__ int lcnt[NBINS], lbase[NBINS];
    int tid = threadIdx.x;
    if (tid < NBINS) lcnt[tid] = 0;
    __syncthreads();

    int g = blockIdx.x * 256 + tid;
    int jlo = 0, jhi = -1;
    int off[3];
    if (g < NG) {
        float4 E = edata[g];
        float s = 0.0f;
#pragma unroll
        for (int q = 0; q < KSPLIT; ++q) s += resp8[(size_t)q * NG + g];
        float es = el_spread[0];
        float amp = s * E.w * (100.0f / (es * 2.5066f)) *
                    (0.3989422804f / 2.23606797749979f);
        float kk = KSCALE / es;
        edata2[g] = make_float4(E.x * kk, E.y * kk, E.z, amp);

        float z = E.z;
        // bins with min |t-z| <= sqrt(180): dropped time terms < e^-18
        jlo = max((int)ceilf((z - 44.5f) * (1.0f / 32.0f)), 0);
        jhi = min((int)floorf((z + 13.5f) * (1.0f / 32.0f)), NBINS - 1);
        for (int j = jlo; j <= jhi; ++j)
            off[j - jlo] = atomicAdd(&lcnt[j], 1);
    }
    __syncthreads();
    if (tid < NBINS) {
        int c = lcnt[tid];
        lbase[tid] = c ? atomicAdd(&cnt[tid], c) : 0;
    }
    __syncthreads();
    for (int j = jlo; j <= jhi; ++j) {
        int p = lbase[j] + off[j - jlo];
        if (p < RCAP) list[j * RCAP + p] = g;
    }
}

// ---------------------------------------------------------------------------
// Kernel 2: B-fragment build, coalesced (two contiguous 16B stores/thread).
// posc stores the pre-scaled positions. (structure verified in R7)
// ---------------------------------------------------------------------------
__global__ __launch_bounds__(256) void k_prof(
    const float4* __restrict__ edata2, const int* __restrict__ cnt,
    const int* __restrict__ list,
    _Float16* __restrict__ bfrag, float2* __restrict__ posc)
{
    __shared__ float4 sE[64];
    int bin = blockIdx.y;
    int tid = threadIdx.x;
    int count = min(cnt[bin], RCAP);
    int nch = (count + 31) >> 5;
    int cbase = blockIdx.x * 2;              // 2 chunks per block
    if (cbase >= nch) return;

    if (tid < 64) {
        int i = cbase * 32 + tid;            // entry index within bin
        float4 E = make_float4(1.0e3f, 1.0e3f, 0.0f, 0.0f);  // pad: amp=0, far
        if (i < count) E = edata2[list[bin * RCAP + i]];
        sE[tid] = E;
        if (i < nch * 32)
            posc[(size_t)bin * RCAP + i] = make_float2(E.x, E.y);
    }
    __syncthreads();

    int ch = cbase + (tid >> 7);
    if (ch >= nch) return;
    int nt = (tid >> 6) & 1;
    int lane = tid & 63;
    int quad = lane >> 4, t16 = lane & 15;
    float tt = (float)(bin * TT + nt * 16 + t16);

    half8 hi, lo;
#pragma unroll
    for (int j = 0; j < 8; ++j) {
        float4 E = sE[(tid >> 7) * 32 + quad * 8 + j];   // LDS broadcast
        float d = tt - E.z;
        float v = E.w * __expf(-0.1f * d * d);
        _Float16 h = (_Float16)v;
        hi[j] = h;
        lo[j] = (_Float16)(v - (float)h);
    }
    size_t base = ((size_t)(bin * CCAP + ch)) * 4 * 512;  // f16 units
    *(half8*)&bfrag[base + (size_t)nt * 512 + lane * 8] = hi;
    *(half8*)&bfrag[base + (size_t)(2 + nt) * 512 + lane * 8] = lo;
}

// ---------------------------------------------------------------------------
// Kernel 3: MFMA main loop with explicit unroll-2 register double-buffer:
// next chunk's bfrag/posc loads issue before current chunk's compute
// (vmcnt pipelining). Gaussian = exp2(-(dx^2+dy^2)) on pre-scaled coords.
// NOTE: pbase quad offset is in float4 units: electrons quad*8..+7 = 8
// float2 = 4 float4 -> "+ quad * 4" (R8's quad*2 was the correctness bug).
// ---------------------------------------------------------------------------
__global__ __launch_bounds__(256) void k_main(
    const _Float16* __restrict__ bfrag, const float2* __restrict__ posc,
    const int* __restrict__ cnt, const float* __restrict__ el_spread,
    const float* __restrict__ sensors, float* __restrict__ part)
{
    int tid = threadIdx.x;
    int wv = tid >> 6, lane = tid & 63;
    int sb = blockIdx.x, bin = blockIdx.y, split = blockIdx.z;
    int quad = lane >> 4;

    int sA = sb * 64 + wv * 16 + (lane & 15);
    float es = el_spread[0];
    float kk = KSCALE / es;
    float sxA = sensors[2 * sA] * kk, syA = sensors[2 * sA + 1] * kk;

    int count = min(cnt[bin], RCAP);
    int nch = (count + 31) >> 5;
    int c0 = nch * split / SPLIT, c1 = nch * (split + 1) / SPLIT;

    floatx4 d0 = {0.f, 0.f, 0.f, 0.f}, d1 = {0.f, 0.f, 0.f, 0.f};

    const half8* bbase = (const half8*)bfrag + (size_t)bin * CCAP * 256 + lane;
    const float4* pbase = (const float4*)(posc + (size_t)bin * RCAP) + quad * 4;

#define LOADC(c, F0, F1, F2, F3, Q0, Q1, Q2, Q3)                          \
    {                                                                     \
        const half8* bb = bbase + (size_t)(c) * 256;                      \
        F0 = bb[0]; F1 = bb[64]; F2 = bb[128]; F3 = bb[192];              \
        const float4* pp = pbase + (size_t)(c) * 16;                      \
        Q0 = pp[0]; Q1 = pp[1]; Q2 = pp[2]; Q3 = pp[3];                   \
    }

#define COMP(F0, F1, F2, F3, Q0, Q1, Q2, Q3)                              \
    {                                                                     \
        float exs[8] = {Q0.x, Q0.z, Q1.x, Q1.z, Q2.x, Q2.z, Q3.x, Q3.z};  \
        float eys[8] = {Q0.y, Q0.w, Q1.y, Q1.w, Q2.y, Q2.w, Q3.y, Q3.w};  \
        half8 ah, al;                                                     \
        _Pragma("unroll")                                                 \
        for (int j = 0; j < 8; ++j) {                                     \
            float dx = sxA - exs[j], dy = syA - eys[j];                   \
            float d2 = fmaf(dy, dy, dx * dx);                             \
            float e = __builtin_amdgcn_exp2f(-d2);                        \
            _Float16 h = (_Float16)e;                                     \
            ah[j] = h;                                                    \
            al[j] = (_Float16)(e - (float)h);                             \
        }                                                                 \
        d0 = __builtin_amdgcn_mfma_f32_16x16x32_f16(ah, F0, d0, 0, 0, 0); \
        d1 = __builtin_amdgcn_mfma_f32_16x16x32_f16(ah, F1, d1, 0, 0, 0); \
        d0 = __builtin_amdgcn_mfma_f32_16x16x32_f16(al, F0, d0, 0, 0, 0); \
        d1 = __builtin_amdgcn_mfma_f32_16x16x32_f16(al, F1, d1, 0, 0, 0); \
        d0 = __builtin_amdgcn_mfma_f32_16x16x32_f16(ah, F2, d0, 0, 0, 0); \
        d1 = __builtin_amdgcn_mfma_f32_16x16x32_f16(ah, F3, d1, 0, 0, 0); \
    }

    if (c0 < c1) {
        half8 fA0, fA1, fA2, fA3, fB0, fB1, fB2, fB3;
        float4 qA0, qA1, qA2, qA3, qB0, qB1, qB2, qB3;
        LOADC(c0, fA0, fA1, fA2, fA3, qA0, qA1, qA2, qA3);
        int c = c0;
        for (; c + 1 < c1; c += 2) {
            LOADC(c + 1, fB0, fB1, fB2, fB3, qB0, qB1, qB2, qB3);
            COMP(fA0, fA1, fA2, fA3, qA0, qA1, qA2, qA3);
            int cn = (c + 2 < c1) ? c + 2 : c1 - 1;
            LOADC(cn, fA0, fA1, fA2, fA3, qA0, qA1, qA2, qA3);
            COMP(fB0, fB1, fB2, fB3, qB0, qB1, qB2, qB3);
        }
        if (c < c1) COMP(fA0, fA1, fA2, fA3, qA0, qA1, qA2, qA3);
    }
#undef LOADC
#undef COMP

    float* pb = part + (((size_t)split * NSB + sb) * NBINS + bin) * 2048;
    int n0 = lane & 15;
#pragma unroll
    for (int r = 0; r < 4; ++r) {
        int sl = wv * 16 + quad * 4 + r;
        pb[sl * 32 + n0]      = d0[r];
        pb[sl * 32 + 16 + n0] = d1[r];
    }
}

// ---------------------------------------------------------------------------
// Kernel 4: reduce split-K partials into output. (unchanged — verified)
// ---------------------------------------------------------------------------
__global__ __launch_bounds__(256) void k_reduce(
    const float4* __restrict__ part, float* __restrict__ out)
{
    int sb = blockIdx.x, bin = blockIdx.y, tid = threadIdx.x;
#pragma unroll
    for (int h = 0; h < 2; ++h) {
        int p = h * 256 + tid;
        int sl = p >> 3, q = p & 7;
        float4 s = make_float4(0.f, 0.f, 0.f, 0.f);
        for (int sp = 0; sp < SPLIT; ++sp) {
            float4 v = part[(((size_t)sp * NSB + sb) * NBINS + bin) * 512 + p];
            s.x += v.x; s.y += v.y; s.z += v.z; s.w += v.w;
        }
        int sensor = sb * 64 + sl;
        *(float4*)(out + (size_t)sensor * Tg + bin * TT + q * 4) = s;
    }
}

// ---------------------------------------------------------------------------
extern "C" void kernel_launch(void* const* d_in, const int* in_sizes, int n_in,
                              void* d_out, int out_size, void* d_ws, size_t ws_size,
                              hipStream_t stream)
{
    const float* sim       = (const float*)d_in[0];
    const float* zpos      = (const float*)d_in[1];
    const float* mask      = (const float*)d_in[2];
    const float* W1        = (const float*)d_in[3];
    const float* b1        = (const float*)d_in[4];
    const float* W2        = (const float*)d_in[5];
    const float* b2        = (const float*)d_in[6];
    const float* W3        = (const float*)d_in[7];
    const float* b3        = (const float*)d_in[8];
    const float* el_spread = (const float*)d_in[9];
    const float* sensors   = (const float*)d_in[10];
    float* out = (float*)d_out;

    char* ws = (char*)d_ws;
    _Float16* bfrag  = (_Float16*)(ws + OFF_BFRAG);
    float2*   posc   = (float2*)(ws + OFF_POSC);
    float*    part   = (float*)(ws + OFF_PART);
    float*    resp8  = (float*)(ws + OFF_RESP8);
    float4*   edata  = (float4*)(ws + OFF_EDATA);
    float4*   edata2 = (float4*)(ws + OFF_EDATA2);
    int*      list   = (int*)(ws + OFF_LIST);
    int*      cnt    = (int*)(ws + OFF_CNT);

    k_mlp<<<dim3((NG / E2 + EB - 1) / EB, KSPLIT), EB, 0, stream>>>(
        sim, zpos, mask, W1, b1, W2, b2, W3, b3, edata, resp8, cnt);

    k_bins<<<(NG + 255) / 256, 256, 0, stream>>>(
        edata, resp8, el_spread, cnt, list, edata2);

    k_prof<<<dim3(CCAP / 2, NBINS), 256, 0, stream>>>(
        edata2, cnt, list, bfrag, posc);

    k_main<<<dim3(NSB, NBINS, SPLIT), 256, 0, stream>>>(
        bfrag, posc, cnt, el_spread, sensors, part);

    k_reduce<<<dim3(NSB, NBINS), 256, 0, stream>>>((const float4*)part, out);
}

// Round 12
// 132.008 us; speedup vs baseline: 2.9738x; 1.0671x over previous
//
#include <hip/hip_runtime.h>
#include <math.h>

// Problem constants
#define NXg 48
#define NYg 48
#define Tg 512
#define NG 20000              // B*NE, batch folded
#define H1g 64
#define H2g 128

// Tiling
#define TT 32                 // ticks per bin
#define NBINS 16
#define RCAP 3072             // per-bin list capacity (max count ~2650)
#define CCAP (RCAP / 32)      // 96 K-chunks max per bin
#define SPLIT 3               // split-K over chunks
#define KSPLIT 8              // H2 split
#define NSB 18                // sensor blocks of 128 (18*128 = 2304)
#define E2 2                  // electrons per thread in k_mlp
#define EB 256                // k_mlp block size

// coordinate pre-scale: exp(-0.5*d2/es^2) = exp2(-(k*d)^2), k = sqrt(0.5*log2 e)/es
#define KSCALE 0.84932180028802f

typedef float vf16 __attribute__((ext_vector_type(16)));
typedef _Float16 half8 __attribute__((ext_vector_type(8)));
typedef float floatx4 __attribute__((ext_vector_type(4)));

// ws layout (bytes)
#define OFF_BFRAG  0                                    //  6,291,456
#define OFF_POSC   (OFF_BFRAG  + (size_t)NBINS*CCAP*4*512*2)
#define OFF_PART   (OFF_POSC   + (size_t)NBINS*RCAP*8)  // 14,155,776
#define OFF_RESP8  (OFF_PART   + (size_t)SPLIT*NSB*NBINS*4096*4)
#define OFF_EDATA  (OFF_RESP8  + (size_t)NG*8*4)
#define OFF_EDATA2 (OFF_EDATA  + (size_t)NG*16)
#define OFF_LIST   (OFF_EDATA2 + (size_t)NG*16)
#define OFF_CNT    (OFF_LIST   + (size_t)NBINS*RCAP*4)
// total ~22.3 MB

// ---------------------------------------------------------------------------
// Kernel 1a: per-electron MLP partials (H2 split 8-way). Also zeroes cnt
// (block (0,0)) — consumed by the LATER k_bins dispatch (safe ordering).
// ---------------------------------------------------------------------------
__global__ __launch_bounds__(EB) void k_mlp(
    const float* __restrict__ sim, const float* __restrict__ zpos,
    const float* __restrict__ mask,
    const float* __restrict__ W1, const float* __restrict__ b1,
    const float* __restrict__ W2, const float* __restrict__ b2,
    const float* __restrict__ W3, const float* __restrict__ b3,
    float4* __restrict__ edata, float* __restrict__ resp8,
    int* __restrict__ cnt)
{
    __shared__ __align__(64) float sW2[H1g][16];
    __shared__ float4 sW1b[H1g];

    int tid = threadIdx.x;
    int q = blockIdx.y;
    int k0 = q * 16;

    if (blockIdx.x == 0 && q == 0 && tid < NBINS) cnt[tid] = 0;

    if (tid < H1g)
        sW1b[tid] = make_float4(W1[tid], W1[H1g + tid], b1[tid], 0.0f);
    if (tid < 256) {
        int j = tid >> 2, c = (tid & 3) * 4;
        *(float4*)&sW2[j][c] = *(const float4*)&W2[j * H2g + k0 + c];
    }
    __syncthreads();

    int g0 = blockIdx.x * EB + tid;
    if (g0 >= NG / E2) return;
    int g1 = g0 + NG / E2;

    float2 s0 = *(const float2*)&sim[2 * g0];
    float2 s1 = *(const float2*)&sim[2 * g1];

    vf16 a0 = *(const vf16*)&b2[k0];
    vf16 a1 = a0;
#pragma unroll 4
    for (int j = 0; j < H1g; ++j) {
        float4 wb = sW1b[j];
        float h0 = fmaxf(fmaf(s0.x, wb.x, fmaf(s0.y, wb.y, wb.z)), 0.0f);
        float h1 = fmaxf(fmaf(s1.x, wb.x, fmaf(s1.y, wb.y, wb.z)), 0.0f);
        vf16 w = *(const vf16*)sW2[j];
#pragma unroll
        for (int u = 0; u < 16; ++u) {
            a0[u] = fmaf(h0, w[u], a0[u]);
            a1[u] = fmaf(h1, w[u], a1[u]);
        }
    }

    float r0 = (q == 0) ? b3[0] : 0.0f;
    float r1 = r0;
#pragma unroll
    for (int u = 0; u < 16; ++u) {
        float w3 = W3[k0 + u];
        r0 = fmaf(fmaxf(a0[u], 0.0f), w3, r0);
        r1 = fmaf(fmaxf(a1[u], 0.0f), w3, r1);
    }
    resp8[(size_t)q * NG + g0] = r0;
    resp8[(size_t)q * NG + g1] = r1;

    if (q == 0) {
        edata[g0] = make_float4(s0.x, s0.y, zpos[g0], mask[g0]);
        edata[g1] = make_float4(s1.x, s1.y, zpos[g1], mask[g1]);
    }
}

// ---------------------------------------------------------------------------
// Kernel 1b: binning (LDS histogram + one global reserve per block,bin)
// fused with amp fold. edata2 = (x*k, y*k, z, amp). (unchanged — verified)
// ---------------------------------------------------------------------------
__global__ __launch_bounds__(256) void k_bins(
    const float4* __restrict__ edata, const float* __restrict__ resp8,
    const float* __restrict__ el_spread,
    int* __restrict__ cnt, int* __restrict__ list, float4* __restrict__ edata2)
{
    __shared__ int lcnt[NBINS], lbase[NBINS];
    int tid = threadIdx.x;
    if (tid < NBINS) lcnt[tid] = 0;
    __syncthreads();

    int g = blockIdx.x * 256 + tid;
    int jlo = 0, jhi = -1;
    int off[3];
    if (g < NG) {
        float4 E = edata[g];
        float s = 0.0f;
#pragma unroll
        for (int q = 0; q < KSPLIT; ++q) s += resp8[(size_t)q * NG + g];
        float es = el_spread[0];
        float amp = s * E.w * (100.0f / (es * 2.5066f)) *
                    (0.3989422804f / 2.23606797749979f);
        float kk = KSCALE / es;
        edata2[g] = make_float4(E.x * kk, E.y * kk, E.z, amp);

        float z = E.z;
        // bins with min |t-z| <= sqrt(180): dropped time terms < e^-18
        jlo = max((int)ceilf((z - 44.5f) * (1.0f / 32.0f)), 0);
        jhi = min((int)floorf((z + 13.5f) * (1.0f / 32.0f)), NBINS - 1);
        for (int j = jlo; j <= jhi; ++j)
            off[j - jlo] = atomicAdd(&lcnt[j], 1);
    }
    __syncthreads();
    if (tid < NBINS) {
        int c = lcnt[tid];
        lbase[tid] = c ? atomicAdd(&cnt[tid], c) : 0;
    }
    __syncthreads();
    for (int j = jlo; j <= jhi; ++j) {
        int p = lbase[j] + off[j - jlo];
        if (p < RCAP) list[j * RCAP + p] = g;
    }
}

// ---------------------------------------------------------------------------
// Kernel 2: B-fragment build, coalesced. (unchanged — verified)
// ---------------------------------------------------------------------------
__global__ __launch_bounds__(256) void k_prof(
    const float4* __restrict__ edata2, const int* __restrict__ cnt,
    const int* __restrict__ list,
    _Float16* __restrict__ bfrag, float2* __restrict__ posc)
{
    __shared__ float4 sE[64];
    int bin = blockIdx.y;
    int tid = threadIdx.x;
    int count = min(cnt[bin], RCAP);
    int nch = (count + 31) >> 5;
    int cbase = blockIdx.x * 2;              // 2 chunks per block
    if (cbase >= nch) return;

    if (tid < 64) {
        int i = cbase * 32 + tid;            // entry index within bin
        float4 E = make_float4(1.0e3f, 1.0e3f, 0.0f, 0.0f);  // pad: amp=0, far
        if (i < count) E = edata2[list[bin * RCAP + i]];
        sE[tid] = E;
        if (i < nch * 32)
            posc[(size_t)bin * RCAP + i] = make_float2(E.x, E.y);
    }
    __syncthreads();

    int ch = cbase + (tid >> 7);
    if (ch >= nch) return;
    int nt = (tid >> 6) & 1;
    int lane = tid & 63;
    int quad = lane >> 4, t16 = lane & 15;
    float tt = (float)(bin * TT + nt * 16 + t16);

    half8 hi, lo;
#pragma unroll
    for (int j = 0; j < 8; ++j) {
        float4 E = sE[(tid >> 7) * 32 + quad * 8 + j];   // LDS broadcast
        float d = tt - E.z;
        float v = E.w * __expf(-0.1f * d * d);
        _Float16 h = (_Float16)v;
        hi[j] = h;
        lo[j] = (_Float16)(v - (float)h);
    }
    size_t base = ((size_t)(bin * CCAP + ch)) * 4 * 512;  // f16 units
    *(half8*)&bfrag[base + (size_t)nt * 512 + lane * 8] = hi;
    *(half8*)&bfrag[base + (size_t)(2 + nt) * 512 + lane * 8] = lo;
}

// ---------------------------------------------------------------------------
// Kernel 3: MFMA main loop, TA-traffic-optimized:
//  - M=32 per wave (two A-tiles share every B load) -> half the B traffic
//  - positions staged ONCE per block into LDS (ds_read, not TA/L1)
//  - unroll-2 register double-buffer on the bfrag (VMEM) loads retained.
// Position address math mirrors R9's VERIFIED global version:
//   float4 index within split = (c-c0)*16 + quad*4 + {0,1,2,3}.
// Block = 4 waves x 32 sensors = 128 sensors; grid (18, 16, SPLIT).
// ---------------------------------------------------------------------------
__global__ __launch_bounds__(256) void k_main(
    const _Float16* __restrict__ bfrag, const float2* __restrict__ posc,
    const int* __restrict__ cnt, const float* __restrict__ el_spread,
    const float* __restrict__ sensors, float* __restrict__ part)
{
    __shared__ float4 sPos[512];           // 32 chunks x 16 float4 = 8 KB max

    int tid = threadIdx.x;
    int wv = tid >> 6, lane = tid & 63;
    int sb = blockIdx.x, bin = blockIdx.y, split = blockIdx.z;
    int quad = lane >> 4;

    int count = min(cnt[bin], RCAP);
    int nch = (count + 31) >> 5;
    int c0 = nch * split / SPLIT, c1 = nch * (split + 1) / SPLIT;
    int nc = c1 - c0;

    // stage this split's positions into LDS: nc chunks x 16 float4
    {
        const float4* psrc = (const float4*)(posc + (size_t)bin * RCAP + c0 * 32);
        for (int i = tid; i < nc * 16; i += 256) sPos[i] = psrc[i];
    }
    __syncthreads();

    int sA = sb * 128 + wv * 32 + (lane & 15);
    float es = el_spread[0];
    float kk = KSCALE / es;
    float sx0 = sensors[2 * sA] * kk,        sy0 = sensors[2 * sA + 1] * kk;
    float sx1 = sensors[2 * (sA + 16)] * kk, sy1 = sensors[2 * (sA + 16) + 1] * kk;

    floatx4 d00 = {0.f,0.f,0.f,0.f}, d01 = {0.f,0.f,0.f,0.f};
    floatx4 d10 = {0.f,0.f,0.f,0.f}, d11 = {0.f,0.f,0.f,0.f};

    const half8* bbase = (const half8*)bfrag + (size_t)bin * CCAP * 256 + lane;
    const float4* lbase = sPos + quad * 4;   // + (c-c0)*16, then 4 consecutive

#define LOADC(c, F0, F1, F2, F3, Q0, Q1, Q2, Q3)                          \
    {                                                                     \
        const half8* bb = bbase + (size_t)(c) * 256;                      \
        F0 = bb[0]; F1 = bb[64]; F2 = bb[128]; F3 = bb[192];              \
        const float4* lp = lbase + ((c) - c0) * 16;                      \
        Q0 = lp[0]; Q1 = lp[1]; Q2 = lp[2]; Q3 = lp[3];                   \
    }

#define COMP(F0, F1, F2, F3, Q0, Q1, Q2, Q3)                              \
    {                                                                     \
        float exs[8] = {Q0.x, Q0.z, Q1.x, Q1.z, Q2.x, Q2.z, Q3.x, Q3.z};  \
        float eys[8] = {Q0.y, Q0.w, Q1.y, Q1.w, Q2.y, Q2.w, Q3.y, Q3.w};  \
        half8 ah0, al0, ah1, al1;                                         \
        _Pragma("unroll")                                                 \
        for (int j = 0; j < 8; ++j) {                                     \
            float dx0 = sx0 - exs[j], dy0 = sy0 - eys[j];                 \
            float dx1 = sx1 - exs[j], dy1 = sy1 - eys[j];                 \
            float e0 = __builtin_amdgcn_exp2f(-fmaf(dy0, dy0, dx0 * dx0));\
            float e1 = __builtin_amdgcn_exp2f(-fmaf(dy1, dy1, dx1 * dx1));\
            _Float16 h0 = (_Float16)e0, h1 = (_Float16)e1;                \
            ah0[j] = h0; al0[j] = (_Float16)(e0 - (float)h0);             \
            ah1[j] = h1; al1[j] = (_Float16)(e1 - (float)h1);             \
        }                                                                 \
        d00 = __builtin_amdgcn_mfma_f32_16x16x32_f16(ah0, F0, d00, 0,0,0);\
        d01 = __builtin_amdgcn_mfma_f32_16x16x32_f16(ah0, F1, d01, 0,0,0);\
        d10 = __builtin_amdgcn_mfma_f32_16x16x32_f16(ah1, F0, d10, 0,0,0);\
        d11 = __builtin_amdgcn_mfma_f32_16x16x32_f16(ah1, F1, d11, 0,0,0);\
        d00 = __builtin_amdgcn_mfma_f32_16x16x32_f16(al0, F0, d00, 0,0,0);\
        d01 = __builtin_amdgcn_mfma_f32_16x16x32_f16(al0, F1, d01, 0,0,0);\
        d10 = __builtin_amdgcn_mfma_f32_16x16x32_f16(al1, F0, d10, 0,0,0);\
        d11 = __builtin_amdgcn_mfma_f32_16x16x32_f16(al1, F1, d11, 0,0,0);\
        d00 = __builtin_amdgcn_mfma_f32_16x16x32_f16(ah0, F2, d00, 0,0,0);\
        d01 = __builtin_amdgcn_mfma_f32_16x16x32_f16(ah0, F3, d01, 0,0,0);\
        d10 = __builtin_amdgcn_mfma_f32_16x16x32_f16(ah1, F2, d10, 0,0,0);\
        d11 = __builtin_amdgcn_mfma_f32_16x16x32_f16(ah1, F3, d11, 0,0,0);\
    }

    if (c0 < c1) {
        half8 fA0, fA1, fA2, fA3, fB0, fB1, fB2, fB3;
        float4 qA0, qA1, qA2, qA3, qB0, qB1, qB2, qB3;
        LOADC(c0, fA0, fA1, fA2, fA3, qA0, qA1, qA2, qA3);
        int c = c0;
        for (; c + 1 < c1; c += 2) {
            LOADC(c + 1, fB0, fB1, fB2, fB3, qB0, qB1, qB2, qB3);
            COMP(fA0, fA1, fA2, fA3, qA0, qA1, qA2, qA3);
            int cn = (c + 2 < c1) ? c + 2 : c1 - 1;
            LOADC(cn, fA0, fA1, fA2, fA3, qA0, qA1, qA2, qA3);
            COMP(fB0, fB1, fB2, fB3, qB0, qB1, qB2, qB3);
        }
        if (c < c1) COMP(fA0, fA1, fA2, fA3, qA0, qA1, qA2, qA3);
    }
#undef LOADC
#undef COMP

    // D layout per tile: row m = quad*4 + r, col n = lane&15
    float* pb = part + (((size_t)split * NSB + sb) * NBINS + bin) * 4096;
    int n0 = lane & 15;
#pragma unroll
    for (int r = 0; r < 4; ++r) {
        int sl0 = wv * 32 + quad * 4 + r;        // M-tile 0
        int sl1 = sl0 + 16;                      // M-tile 1
        pb[sl0 * 32 + n0]      = d00[r];
        pb[sl0 * 32 + 16 + n0] = d01[r];
        pb[sl1 * 32 + n0]      = d10[r];
        pb[sl1 * 32 + 16 + n0] = d11[r];
    }
}

// ---------------------------------------------------------------------------
// Kernel 4: reduce split-K partials into output (128 sensors per sb).
// ---------------------------------------------------------------------------
__global__ __launch_bounds__(256) void k_reduce(
    const float4* __restrict__ part, float* __restrict__ out)
{
    int sb = blockIdx.x, bin = blockIdx.y, tid = threadIdx.x;
#pragma unroll
    for (int h = 0; h < 4; ++h) {
        int p = h * 256 + tid;            // float4 index within 1024
        int sl = p >> 3, q = p & 7;
        float4 s = make_float4(0.f, 0.f, 0.f, 0.f);
        for (int sp = 0; sp < SPLIT; ++sp) {
            float4 v = part[(((size_t)sp * NSB + sb) * NBINS + bin) * 1024 + p];
            s.x += v.x; s.y += v.y; s.z += v.z; s.w += v.w;
        }
        int sensor = sb * 128 + sl;
        *(float4*)(out + (size_t)sensor * Tg + bin * TT + q * 4) = s;
    }
}

// ---------------------------------------------------------------------------
extern "C" void kernel_launch(void* const* d_in, const int* in_sizes, int n_in,
                              void* d_out, int out_size, void* d_ws, size_t ws_size,
                              hipStream_t stream)
{
    const float* sim       = (const float*)d_in[0];
    const float* zpos      = (const float*)d_in[1];
    const float* mask      = (const float*)d_in[2];
    const float* W1        = (const float*)d_in[3];
    const float* b1        = (const float*)d_in[4];
    const float* W2        = (const float*)d_in[5];
    const float* b2        = (const float*)d_in[6];
    const float* W3        = (const float*)d_in[7];
    const float* b3        = (const float*)d_in[8];
    const float* el_spread = (const float*)d_in[9];
    const float* sensors   = (const float*)d_in[10];
    float* out = (float*)d_out;

    char* ws = (char*)d_ws;
    _Float16* bfrag  = (_Float16*)(ws + OFF_BFRAG);
    float2*   posc   = (float2*)(ws + OFF_POSC);
    float*    part   = (float*)(ws + OFF_PART);
    float*    resp8  = (float*)(ws + OFF_RESP8);
    float4*   edata  = (float4*)(ws + OFF_EDATA);
    float4*   edata2 = (float4*)(ws + OFF_EDATA2);
    int*      list   = (int*)(ws + OFF_LIST);
    int*      cnt    = (int*)(ws + OFF_CNT);

    k_mlp<<<dim3((NG / E2 + EB - 1) / EB, KSPLIT), EB, 0, stream>>>(
        sim, zpos, mask, W1, b1, W2, b2, W3, b3, edata, resp8, cnt);

    k_bins<<<(NG + 255) / 256, 256, 0, stream>>>(
        edata, resp8, el_spread, cnt, list, edata2);

    k_prof<<<dim3(CCAP / 2, NBINS), 256, 0, stream>>>(
        edata2, cnt, list, bfrag, posc);

    k_main<<<dim3(NSB, NBINS, SPLIT), 256, 0, stream>>>(
        bfrag, posc, cnt, el_spread, sensors, part);

    k_reduce<<<dim3(NSB, NBINS), 256, 0, stream>>>((const float4*)part, out);
}